// Round 1
// baseline (3351.947 us; speedup 1.0000x reference)
//
#include <hip/hip_runtime.h>
#include <hip/hip_bf16.h>
#include <math.h>

#define NXC 4096
#define NNODES 32768       // B*NX = 8*4096
#define LSTR 260           // padded LDS row stride (floats), 16B-aligned rows, bank-friendly

__device__ __forceinline__ float gelu_f(float v) {
    return 0.5f * v * (1.0f + erff(v * 0.70710678118654752f));
}

// ---------------- tau terms (per batch): TM/TG/TU = tau @ W1_tau + b1 ----------------
__global__ void tau_kernel(const float* __restrict__ tau,
                           const float* __restrict__ msg_w1, const float* __restrict__ msg_b1,
                           const float* __restrict__ gate_w1, const float* __restrict__ gate_b1,
                           const float* __restrict__ upd_w1, const float* __restrict__ upd_b1,
                           float* __restrict__ TM, float* __restrict__ TG, float* __restrict__ TU)
{
    const int b = blockIdx.x;      // 0..7
    const int t = threadIdx.x;     // 0..255
    float tv[16];
    #pragma unroll
    for (int k = 0; k < 16; ++k) tv[k] = tau[b*16 + k];
    float am = msg_b1[t], ag = gate_b1[t], au = upd_b1[t];
    #pragma unroll
    for (int k = 0; k < 16; ++k) {
        am = fmaf(tv[k], msg_w1 [(257+k)*256 + t], am);
        ag = fmaf(tv[k], gate_w1[(257+k)*256 + t], ag);
        au = fmaf(tv[k], upd_w1 [(256+k)*256 + t], au);
    }
    TM[b*256+t] = am; TG[b*256+t] = ag; TU[b*256+t] = au;
}

// ---------------- per-node precompute: PA/PB (msg,gate), HU, HL ----------------
__device__ __forceinline__ void gemm_h_tile(const float hs[16][128], const float* __restrict__ W,
                                            __hip_bfloat16* __restrict__ O, int base, int t)
{
    float acc[16];
    #pragma unroll
    for (int nd = 0; nd < 16; ++nd) acc[nd] = 0.f;
    for (int k4 = 0; k4 < 128; k4 += 4) {
        float w0 = W[(k4+0)*256 + t];
        float w1 = W[(k4+1)*256 + t];
        float w2 = W[(k4+2)*256 + t];
        float w3 = W[(k4+3)*256 + t];
        #pragma unroll
        for (int nd = 0; nd < 16; ++nd) {
            float4 hv = *(const float4*)&hs[nd][k4];
            acc[nd] = fmaf(hv.x, w0, acc[nd]);
            acc[nd] = fmaf(hv.y, w1, acc[nd]);
            acc[nd] = fmaf(hv.z, w2, acc[nd]);
            acc[nd] = fmaf(hv.w, w3, acc[nd]);
        }
    }
    #pragma unroll
    for (int nd = 0; nd < 16; ++nd)
        O[(size_t)(base+nd)*256 + t] = __float2bfloat16(acc[nd]);
}

__global__ __launch_bounds__(256)
void precompute_kernel(const float* __restrict__ h,
                       const float* __restrict__ msg_w1, const float* __restrict__ gate_w1,
                       const float* __restrict__ upd_w1,
                       const float* __restrict__ W_w, const float* __restrict__ W_b,
                       __hip_bfloat16* __restrict__ PAm, __hip_bfloat16* __restrict__ PBm,
                       __hip_bfloat16* __restrict__ PAg, __hip_bfloat16* __restrict__ PBg,
                       __hip_bfloat16* __restrict__ HU, float* __restrict__ HL)
{
    __shared__ __align__(16) float hs[16][128];
    const int t = threadIdx.x;
    const int base = blockIdx.x * 16;
    for (int idx = t; idx < 16*128; idx += 256)
        hs[idx >> 7][idx & 127] = h[(size_t)base*128 + idx];
    __syncthreads();

    gemm_h_tile(hs, msg_w1,              PAm, base, t);   // rows 0..127
    gemm_h_tile(hs, msg_w1 + 128*256,    PBm, base, t);   // rows 128..255
    gemm_h_tile(hs, gate_w1,             PAg, base, t);
    gemm_h_tile(hs, gate_w1 + 128*256,   PBg, base, t);
    gemm_h_tile(hs, upd_w1,              HU,  base, t);   // rows 0..127 of upd_w1

    // HL = h @ W_w + W_b  (128 cols)
    {
        const int col = t & 127;
        const int half = t >> 7;  // 0/1
        float wb = W_b[col];
        for (int nd = half; nd < 16; nd += 2) {
            float acc = wb;
            for (int k4 = 0; k4 < 128; k4 += 4) {
                float4 hv = *(const float4*)&hs[nd][k4];
                acc = fmaf(hv.x, W_w[(k4+0)*128+col], acc);
                acc = fmaf(hv.y, W_w[(k4+1)*128+col], acc);
                acc = fmaf(hv.z, W_w[(k4+2)*128+col], acc);
                acc = fmaf(hv.w, W_w[(k4+3)*128+col], acc);
            }
            HL[(size_t)(base+nd)*128 + col] = acc;
        }
    }
}

// ---------------- edge kernel: layer1(decomposed) -> gate -> layer2 -> layer3 -> agg ----------------
#define NPB 4    // nodes per block
#define EPB 28   // edges per block (7*NPB)

__global__ __launch_bounds__(256, 2)
void edge_kernel(const float* __restrict__ x, const float* __restrict__ u0,
                 const float* __restrict__ msg_w1, const float* __restrict__ gate_w1,
                 const float* __restrict__ msg_w2, const float* __restrict__ msg_b2,
                 const float* __restrict__ msg_w3, const float* __restrict__ msg_b3,
                 const float* __restrict__ gate_w2, const float* __restrict__ gate_b2,
                 const __hip_bfloat16* __restrict__ PAm, const __hip_bfloat16* __restrict__ PBm,
                 const __hip_bfloat16* __restrict__ PAg, const __hip_bfloat16* __restrict__ PBg,
                 const float* __restrict__ TM, const float* __restrict__ TG,
                 float* __restrict__ AGG)
{
    __shared__ __align__(16) float A [32][LSTR];  // a1, later msg*gate
    __shared__ __align__(16) float Bf[32][LSTR];  // gate-prod, later a2
    __shared__ float s_rel[EPB], s_du[EPB], s_ad[EPB];
    __shared__ int   s_j[EPB];
    __shared__ float s_gate[EPB];

    const int t = threadIdx.x;
    const int base = blockIdx.x * NPB;
    const int b = base / NXC;

    if (t < EPB) {
        int nd = t / 7, s = t % 7;
        int i  = base + nd;
        int ii = i - b*NXC;
        int jj = ii + s - 3;
        jj = jj < 0 ? 0 : (jj > NXC-1 ? NXC-1 : jj);
        int j = b*NXC + jj;
        s_j[t] = j;
        float rel = x[j] - x[i];
        float du  = u0[i] - u0[j];
        s_rel[t] = rel; s_du[t] = du; s_ad[t] = fabsf(du);
    }
    __syncthreads();

    // phase 1: decomposed layer-1 for msg and gate, column t for all 28 edges
    {
        float wr  = msg_w1 [256*256+t], wd  = msg_w1 [273*256+t], wa  = msg_w1 [274*256+t];
        float gwr = gate_w1[256*256+t], gwd = gate_w1[273*256+t], gwa = gate_w1[274*256+t];
        float tm = TM[b*256+t], tg = TG[b*256+t];
        float gw2t = gate_w2[t];
        float pam[NPB], pag[NPB];
        #pragma unroll
        for (int nd = 0; nd < NPB; ++nd) {
            pam[nd] = __bfloat162float(PAm[(size_t)(base+nd)*256 + t]);
            pag[nd] = __bfloat162float(PAg[(size_t)(base+nd)*256 + t]);
        }
        #pragma unroll
        for (int e = 0; e < EPB; ++e) {
            const int nd = e / 7;
            const int j = s_j[e];
            float pbm = __bfloat162float(PBm[(size_t)j*256 + t]);
            float pbg = __bfloat162float(PBg[(size_t)j*256 + t]);
            float rel = s_rel[e], du = s_du[e], ad = s_ad[e];
            float pm = pam[nd] + pbm + tm;
            pm = fmaf(rel, wr, pm); pm = fmaf(du, wd, pm); pm = fmaf(ad, wa, pm);
            A[e][t] = gelu_f(pm);
            float pg = pag[nd] + pbg + tg;
            pg = fmaf(rel, gwr, pg); pg = fmaf(du, gwd, pg); pg = fmaf(ad, gwa, pg);
            Bf[e][t] = gelu_f(pg) * gw2t;
        }
        #pragma unroll
        for (int e = EPB; e < 32; ++e) { A[e][t] = 0.f; Bf[e][t] = 0.f; }
    }
    __syncthreads();

    // gate reduce: wave w handles edges w*7 .. w*7+6
    {
        const int wv = t >> 6, lane = t & 63;
        const float gb2 = gate_b2[0];
        for (int q = 0; q < 7; ++q) {
            int e = wv*7 + q;
            float v = Bf[e][lane] + Bf[e][lane+64] + Bf[e][lane+128] + Bf[e][lane+192];
            #pragma unroll
            for (int off = 32; off > 0; off >>= 1) v += __shfl_xor(v, off);
            if (lane == 0) s_gate[e] = 1.f / (1.f + expf(-(v + gb2)));
        }
    }
    __syncthreads();

    // phase 2: a2 = gelu(a1 @ msg_w2 + b2). thread = (edge e, col-group g of 32)
    {
        const int e = t & 31;
        const int g = t >> 5;
        float acc[32];
        #pragma unroll
        for (int c4 = 0; c4 < 8; ++c4) {
            float4 bv = *(const float4*)&msg_b2[g*32 + c4*4];
            acc[c4*4+0]=bv.x; acc[c4*4+1]=bv.y; acc[c4*4+2]=bv.z; acc[c4*4+3]=bv.w;
        }
        for (int k4 = 0; k4 < 256; k4 += 4) {
            float4 av = *(const float4*)&A[e][k4];
            float as[4] = {av.x, av.y, av.z, av.w};
            #pragma unroll
            for (int kk = 0; kk < 4; ++kk) {
                const float4* w4 = (const float4*)&msg_w2[(size_t)(k4+kk)*256 + g*32];
                #pragma unroll
                for (int c4 = 0; c4 < 8; ++c4) {
                    float4 w = w4[c4];
                    acc[c4*4+0] = fmaf(as[kk], w.x, acc[c4*4+0]);
                    acc[c4*4+1] = fmaf(as[kk], w.y, acc[c4*4+1]);
                    acc[c4*4+2] = fmaf(as[kk], w.z, acc[c4*4+2]);
                    acc[c4*4+3] = fmaf(as[kk], w.w, acc[c4*4+3]);
                }
            }
        }
        __syncthreads();  // gate-reduce finished reading Bf (already barriered) ; ensure all A reads done before... A untouched; barrier orders Bf rewrite vs phase-3 start
        #pragma unroll
        for (int c = 0; c < 32; ++c) Bf[e][g*32 + c] = gelu_f(acc[c]);
    }
    __syncthreads();

    // phase 3: msg = a2 @ msg_w3 + b3; fold gate. thread = (edge e, col-group g of 16)
    {
        const int e = t & 31;
        const int g = t >> 5;
        float acc[16];
        #pragma unroll
        for (int c4 = 0; c4 < 4; ++c4) {
            float4 bv = *(const float4*)&msg_b3[g*16 + c4*4];
            acc[c4*4+0]=bv.x; acc[c4*4+1]=bv.y; acc[c4*4+2]=bv.z; acc[c4*4+3]=bv.w;
        }
        for (int k4 = 0; k4 < 256; k4 += 4) {
            float4 av = *(const float4*)&Bf[e][k4];
            float as[4] = {av.x, av.y, av.z, av.w};
            #pragma unroll
            for (int kk = 0; kk < 4; ++kk) {
                const float4* w4 = (const float4*)&msg_w3[(size_t)(k4+kk)*128 + g*16];
                #pragma unroll
                for (int c4 = 0; c4 < 4; ++c4) {
                    float4 w = w4[c4];
                    acc[c4*4+0] = fmaf(as[kk], w.x, acc[c4*4+0]);
                    acc[c4*4+1] = fmaf(as[kk], w.y, acc[c4*4+1]);
                    acc[c4*4+2] = fmaf(as[kk], w.z, acc[c4*4+2]);
                    acc[c4*4+3] = fmaf(as[kk], w.w, acc[c4*4+3]);
                }
            }
        }
        const float gate = (e < EPB) ? s_gate[e] : 0.f;
        __syncthreads();   // all Bf reads done before A is overwritten (A unread since phase 2)
        #pragma unroll
        for (int c = 0; c < 16; ++c) A[e][g*16 + c] = acc[c] * gate;
    }
    __syncthreads();

    // aggregate over the 7 edges of each node
    {
        const int col = t & 127;
        const int h2 = t >> 7;
        #pragma unroll
        for (int p = 0; p < 2; ++p) {
            int nd = h2*2 + p;
            float s = 0.f;
            #pragma unroll
            for (int q = 0; q < 7; ++q) s += A[nd*7 + q][col];
            AGG[(size_t)(base+nd)*128 + col] = s;
        }
    }
}

// ---------------- update kernel: u1,u2,u3 + local + final gelu ----------------
#define NTU 8
__global__ __launch_bounds__(256)
void update_kernel(const float* __restrict__ upd_w1,
                   const float* __restrict__ upd_w2, const float* __restrict__ upd_b2,
                   const float* __restrict__ upd_w3, const float* __restrict__ upd_b3,
                   const __hip_bfloat16* __restrict__ HU, const float* __restrict__ HL,
                   const float* __restrict__ AGG, const float* __restrict__ TU,
                   float* __restrict__ out)
{
    __shared__ __align__(16) float aggs[NTU][128];
    __shared__ __align__(16) float U1[NTU][LSTR];
    __shared__ __align__(16) float U2[NTU][LSTR];
    const int t = threadIdx.x;
    const int base = blockIdx.x * NTU;
    const int b = base / NXC;

    for (int idx = t; idx < NTU*128; idx += 256)
        aggs[idx >> 7][idx & 127] = AGG[(size_t)base*128 + idx];
    __syncthreads();

    // u1 = gelu(HU + agg @ upd_w1[128:256] + TU)
    {
        float tu = TU[b*256 + t];
        float acc[NTU];
        #pragma unroll
        for (int nd = 0; nd < NTU; ++nd)
            acc[nd] = tu + __bfloat162float(HU[(size_t)(base+nd)*256 + t]);
        for (int k4 = 0; k4 < 128; k4 += 4) {
            float w0 = upd_w1[(size_t)(128+k4+0)*256+t];
            float w1 = upd_w1[(size_t)(128+k4+1)*256+t];
            float w2 = upd_w1[(size_t)(128+k4+2)*256+t];
            float w3 = upd_w1[(size_t)(128+k4+3)*256+t];
            #pragma unroll
            for (int nd = 0; nd < NTU; ++nd) {
                float4 av = *(const float4*)&aggs[nd][k4];
                acc[nd] = fmaf(av.x, w0, acc[nd]);
                acc[nd] = fmaf(av.y, w1, acc[nd]);
                acc[nd] = fmaf(av.z, w2, acc[nd]);
                acc[nd] = fmaf(av.w, w3, acc[nd]);
            }
        }
        #pragma unroll
        for (int nd = 0; nd < NTU; ++nd) U1[nd][t] = gelu_f(acc[nd]);
    }
    __syncthreads();

    // u2 = gelu(u1 @ upd_w2 + b2)
    {
        float acc[NTU];
        float bb = upd_b2[t];
        #pragma unroll
        for (int nd = 0; nd < NTU; ++nd) acc[nd] = bb;
        for (int k4 = 0; k4 < 256; k4 += 4) {
            float w0 = upd_w2[(size_t)(k4+0)*256+t];
            float w1 = upd_w2[(size_t)(k4+1)*256+t];
            float w2 = upd_w2[(size_t)(k4+2)*256+t];
            float w3 = upd_w2[(size_t)(k4+3)*256+t];
            #pragma unroll
            for (int nd = 0; nd < NTU; ++nd) {
                float4 uv = *(const float4*)&U1[nd][k4];
                acc[nd] = fmaf(uv.x, w0, acc[nd]);
                acc[nd] = fmaf(uv.y, w1, acc[nd]);
                acc[nd] = fmaf(uv.z, w2, acc[nd]);
                acc[nd] = fmaf(uv.w, w3, acc[nd]);
            }
        }
        #pragma unroll
        for (int nd = 0; nd < NTU; ++nd) U2[nd][t] = gelu_f(acc[nd]);
    }
    __syncthreads();

    // u3 + local + gelu
    {
        const int col = t & 127;
        const int h2 = t >> 7;
        float b3 = upd_b3[col];
        float acc[4] = {b3, b3, b3, b3};
        for (int k4 = 0; k4 < 256; k4 += 4) {
            #pragma unroll
            for (int kk = 0; kk < 4; ++kk) {
                float w = upd_w3[(size_t)(k4+kk)*128 + col];
                #pragma unroll
                for (int p = 0; p < 4; ++p)
                    acc[p] = fmaf(U2[h2*4+p][k4+kk], w, acc[p]);
            }
        }
        #pragma unroll
        for (int p = 0; p < 4; ++p) {
            int nd = h2*4 + p;
            size_t o = (size_t)(base+nd)*128 + col;
            out[o] = gelu_f(acc[p] + HL[o]);
        }
    }
}

// ---------------- launch ----------------
extern "C" void kernel_launch(void* const* d_in, const int* in_sizes, int n_in,
                              void* d_out, int out_size, void* d_ws, size_t ws_size,
                              hipStream_t stream)
{
    const float* h      = (const float*)d_in[0];
    const float* x      = (const float*)d_in[1];
    const float* tau    = (const float*)d_in[2];
    const float* u0     = (const float*)d_in[3];
    const float* msg_w1 = (const float*)d_in[4];
    const float* msg_b1 = (const float*)d_in[5];
    const float* msg_w2 = (const float*)d_in[6];
    const float* msg_b2 = (const float*)d_in[7];
    const float* msg_w3 = (const float*)d_in[8];
    const float* msg_b3 = (const float*)d_in[9];
    const float* gate_w1= (const float*)d_in[10];
    const float* gate_b1= (const float*)d_in[11];
    const float* gate_w2= (const float*)d_in[12];
    const float* gate_b2= (const float*)d_in[13];
    const float* upd_w1 = (const float*)d_in[14];
    const float* upd_b1 = (const float*)d_in[15];
    const float* upd_w2 = (const float*)d_in[16];
    const float* upd_b2 = (const float*)d_in[17];
    const float* upd_w3 = (const float*)d_in[18];
    const float* upd_b3 = (const float*)d_in[19];
    const float* W_w    = (const float*)d_in[20];
    const float* W_b    = (const float*)d_in[21];
    float* out = (float*)d_out;

    char* ws = (char*)d_ws;
    size_t off = 0;
    auto alloc = [&](size_t bytes) -> void* {
        void* p = ws + off;
        off += (bytes + 255) & ~(size_t)255;
        return p;
    };
    __hip_bfloat16* PAm = (__hip_bfloat16*)alloc((size_t)NNODES*256*2);
    __hip_bfloat16* PBm = (__hip_bfloat16*)alloc((size_t)NNODES*256*2);
    __hip_bfloat16* PAg = (__hip_bfloat16*)alloc((size_t)NNODES*256*2);
    __hip_bfloat16* PBg = (__hip_bfloat16*)alloc((size_t)NNODES*256*2);
    __hip_bfloat16* HU  = (__hip_bfloat16*)alloc((size_t)NNODES*256*2);
    float* HL  = (float*)alloc((size_t)NNODES*128*4);
    float* AGG = (float*)alloc((size_t)NNODES*128*4);
    float* TM  = (float*)alloc(8*256*4);
    float* TG  = (float*)alloc(8*256*4);
    float* TU  = (float*)alloc(8*256*4);
    (void)ws_size; (void)in_sizes; (void)n_in; (void)out_size;

    tau_kernel<<<8, 256, 0, stream>>>(tau, msg_w1, msg_b1, gate_w1, gate_b1,
                                      upd_w1, upd_b1, TM, TG, TU);
    precompute_kernel<<<NNODES/16, 256, 0, stream>>>(h, msg_w1, gate_w1, upd_w1,
                                                     W_w, W_b, PAm, PBm, PAg, PBg, HU, HL);
    edge_kernel<<<NNODES/NPB, 256, 0, stream>>>(x, u0, msg_w1, gate_w1,
                                                msg_w2, msg_b2, msg_w3, msg_b3,
                                                gate_w2, gate_b2,
                                                PAm, PBm, PAg, PBg, TM, TG, AGG);
    update_kernel<<<NNODES/NTU, 256, 0, stream>>>(upd_w1, upd_w2, upd_b2, upd_w3, upd_b3,
                                                  HU, HL, AGG, TU, out);
}

// Round 2
// 749.696 us; speedup vs baseline: 4.4711x; 4.4711x over previous
//
#include <hip/hip_runtime.h>
#include <hip/hip_bf16.h>
#include <math.h>

#define NXC 4096
#define NNODES 32768       // B*NX = 8*4096
#define LSTR 260           // padded LDS row stride (floats) for VALU kernels

typedef __attribute__((ext_vector_type(8))) short bf16x8;
typedef __attribute__((ext_vector_type(16))) float f32x16;

#define MFMA32(a,b,c) __builtin_amdgcn_mfma_f32_32x32x16_bf16((a),(b),(c),0,0,0)

__device__ __forceinline__ float gelu_f(float v) {
    return 0.5f * v * (1.0f + erff(v * 0.70710678118654752f));
}

__device__ __forceinline__ f32x16 zero16() {
    f32x16 v;
    #pragma unroll
    for (int i = 0; i < 16; ++i) v[i] = 0.f;
    return v;
}

// ---------------- tau terms (per batch): TM/TG/TU = tau @ W1_tau + b1 ----------------
__global__ void tau_kernel(const float* __restrict__ tau,
                           const float* __restrict__ msg_w1, const float* __restrict__ msg_b1,
                           const float* __restrict__ gate_w1, const float* __restrict__ gate_b1,
                           const float* __restrict__ upd_w1, const float* __restrict__ upd_b1,
                           float* __restrict__ TM, float* __restrict__ TG, float* __restrict__ TU)
{
    const int b = blockIdx.x;      // 0..7
    const int t = threadIdx.x;     // 0..255
    float tv[16];
    #pragma unroll
    for (int k = 0; k < 16; ++k) tv[k] = tau[b*16 + k];
    float am = msg_b1[t], ag = gate_b1[t], au = upd_b1[t];
    #pragma unroll
    for (int k = 0; k < 16; ++k) {
        am = fmaf(tv[k], msg_w1 [(257+k)*256 + t], am);
        ag = fmaf(tv[k], gate_w1[(257+k)*256 + t], ag);
        au = fmaf(tv[k], upd_w1 [(256+k)*256 + t], au);
    }
    TM[b*256+t] = am; TG[b*256+t] = ag; TU[b*256+t] = au;
}

// ---------------- weight prep: bf16-transposed msg_w2 / msg_w3 ----------------
__global__ void wconv_kernel(const float* __restrict__ w2, const float* __restrict__ w3,
                             __hip_bfloat16* __restrict__ w2t, __hip_bfloat16* __restrict__ w3t)
{
    int t = blockIdx.x * 256 + threadIdx.x;
    if (t < 256*256) {
        int c = t >> 8, k = t & 255;
        w2t[c*256 + k] = __float2bfloat16(w2[k*256 + c]);   // w2t[c][k] = w2[k][c]
    }
    if (t < 128*256) {
        int c = t >> 8, k = t & 255;
        w3t[c*256 + k] = __float2bfloat16(w3[k*128 + c]);   // w3t[c][k] = w3[k][c]
    }
}

// ---------------- per-node precompute: PA/PB (msg,gate), HU, HL ----------------
__device__ __forceinline__ void gemm_h_tile(const float hs[16][128], const float* __restrict__ W,
                                            __hip_bfloat16* __restrict__ O, int base, int t)
{
    float acc[16];
    #pragma unroll
    for (int nd = 0; nd < 16; ++nd) acc[nd] = 0.f;
    for (int k4 = 0; k4 < 128; k4 += 4) {
        float w0 = W[(k4+0)*256 + t];
        float w1 = W[(k4+1)*256 + t];
        float w2 = W[(k4+2)*256 + t];
        float w3 = W[(k4+3)*256 + t];
        #pragma unroll
        for (int nd = 0; nd < 16; ++nd) {
            float4 hv = *(const float4*)&hs[nd][k4];
            acc[nd] = fmaf(hv.x, w0, acc[nd]);
            acc[nd] = fmaf(hv.y, w1, acc[nd]);
            acc[nd] = fmaf(hv.z, w2, acc[nd]);
            acc[nd] = fmaf(hv.w, w3, acc[nd]);
        }
    }
    #pragma unroll
    for (int nd = 0; nd < 16; ++nd)
        O[(size_t)(base+nd)*256 + t] = __float2bfloat16(acc[nd]);
}

__global__ __launch_bounds__(256)
void precompute_kernel(const float* __restrict__ h,
                       const float* __restrict__ msg_w1, const float* __restrict__ gate_w1,
                       const float* __restrict__ upd_w1,
                       const float* __restrict__ W_w, const float* __restrict__ W_b,
                       __hip_bfloat16* __restrict__ PAm, __hip_bfloat16* __restrict__ PBm,
                       __hip_bfloat16* __restrict__ PAg, __hip_bfloat16* __restrict__ PBg,
                       __hip_bfloat16* __restrict__ HU, float* __restrict__ HL)
{
    __shared__ __align__(16) float hs[16][128];
    const int t = threadIdx.x;
    const int base = blockIdx.x * 16;
    for (int idx = t; idx < 16*128; idx += 256)
        hs[idx >> 7][idx & 127] = h[(size_t)base*128 + idx];
    __syncthreads();

    gemm_h_tile(hs, msg_w1,              PAm, base, t);   // rows 0..127
    gemm_h_tile(hs, msg_w1 + 128*256,    PBm, base, t);   // rows 128..255
    gemm_h_tile(hs, gate_w1,             PAg, base, t);
    gemm_h_tile(hs, gate_w1 + 128*256,   PBg, base, t);
    gemm_h_tile(hs, upd_w1,              HU,  base, t);   // rows 0..127 of upd_w1

    // HL = h @ W_w + W_b  (128 cols)
    {
        const int col = t & 127;
        const int half = t >> 7;  // 0/1
        float wb = W_b[col];
        for (int nd = half; nd < 16; nd += 2) {
            float acc = wb;
            for (int k4 = 0; k4 < 128; k4 += 4) {
                float4 hv = *(const float4*)&hs[nd][k4];
                acc = fmaf(hv.x, W_w[(k4+0)*128+col], acc);
                acc = fmaf(hv.y, W_w[(k4+1)*128+col], acc);
                acc = fmaf(hv.z, W_w[(k4+2)*128+col], acc);
                acc = fmaf(hv.w, W_w[(k4+3)*128+col], acc);
            }
            HL[(size_t)(base+nd)*128 + col] = acc;
        }
    }
}

// ---------------- fused edge kernel: layer1(VALU) -> MFMA layer2 -> MFMA layer3 -> agg ----------------
#define ENPB 8     // nodes per block
#define EEPB 56    // edges per block
#define EM   64    // padded M (rows) for MFMA
#define ARS  264   // a1/a2 row stride in bf16 elems (528 B, odd 16B-chunk stride)
#define MRS  132   // msgbuf row stride in f32 elems (528 B)

__global__ __launch_bounds__(256, 2)
void edge_kernel(const float* __restrict__ x, const float* __restrict__ u0,
                 const float* __restrict__ msg_w1, const float* __restrict__ gate_w1,
                 const __hip_bfloat16* __restrict__ w2t, const float* __restrict__ msg_b2,
                 const __hip_bfloat16* __restrict__ w3t, const float* __restrict__ msg_b3,
                 const float* __restrict__ gate_w2, const float* __restrict__ gate_b2,
                 const __hip_bfloat16* __restrict__ PAm, const __hip_bfloat16* __restrict__ PBm,
                 const __hip_bfloat16* __restrict__ PAg, const __hip_bfloat16* __restrict__ PBg,
                 const float* __restrict__ TM, const float* __restrict__ TG,
                 float* __restrict__ AGG)
{
    __shared__ __align__(16) __hip_bfloat16 a1[EM*ARS];
    __shared__ __align__(16) __hip_bfloat16 a2[EM*ARS];
    __shared__ float s_rel[EEPB], s_du[EEPB], s_ad[EEPB];
    __shared__ int   s_slotj[14];
    __shared__ float s_gpart[4][EEPB];
    __shared__ float s_gate[EM];

    const int t    = threadIdx.x;
    const int lane = t & 63;
    const int wv   = t >> 6;
    const int base = blockIdx.x * ENPB;
    const int b    = base >> 12;          // /NXC
    const int ii0  = base & (NXC-1);

    if (t < 14) {
        int jj = ii0 - 3 + t;
        jj = jj < 0 ? 0 : (jj > NXC-1 ? NXC-1 : jj);
        s_slotj[t] = b*NXC + jj;
    }
    if (t < EEPB) {
        int nd = t / 7, s = t - nd*7;
        int i  = base + nd;
        int jj = ii0 + nd + s - 3;
        jj = jj < 0 ? 0 : (jj > NXC-1 ? NXC-1 : jj);
        int j = b*NXC + jj;
        float rel = x[j] - x[i];
        float du  = u0[i] - u0[j];
        s_rel[t] = rel; s_du[t] = du; s_ad[t] = fabsf(du);
    }
    {   // zero a1 pad rows 56..63 (the 512 data bytes of each row)
        int r = 56 + (t >> 5);
        float4 z = {0.f, 0.f, 0.f, 0.f};
        *(float4*)((char*)a1 + (size_t)r*528 + (size_t)(t & 31)*16) = z;
    }
    __syncthreads();

    // ---- phase 1: decomposed layer-1 for msg (-> a1 LDS) and gate (-> s_gpart) ----
    {
        float wr  = msg_w1 [256*256+t], wd  = msg_w1 [273*256+t], wa  = msg_w1 [274*256+t];
        float gwr = gate_w1[256*256+t], gwd = gate_w1[273*256+t], gwa = gate_w1[274*256+t];
        float tm = TM[b*256+t], tg = TG[b*256+t];
        float g2 = gate_w2[t];
        float pbm[14], pbg[14], pam[8], pag[8];
        #pragma unroll
        for (int q = 0; q < 14; ++q) {
            size_t o = (size_t)s_slotj[q]*256 + t;
            pbm[q] = __bfloat162float(PBm[o]);
            pbg[q] = __bfloat162float(PBg[o]);
        }
        #pragma unroll
        for (int nd = 0; nd < 8; ++nd) {
            size_t o = (size_t)(base+nd)*256 + t;
            pam[nd] = __bfloat162float(PAm[o]);
            pag[nd] = __bfloat162float(PAg[o]);
        }
        #pragma unroll
        for (int nd = 0; nd < 8; ++nd) {
            #pragma unroll
            for (int s = 0; s < 7; ++s) {
                const int e = nd*7 + s, q = nd + s;
                float rel = s_rel[e], du = s_du[e], ad = s_ad[e];
                float pm = pam[nd] + pbm[q] + tm;
                pm = fmaf(rel, wr, pm); pm = fmaf(du, wd, pm); pm = fmaf(ad, wa, pm);
                a1[e*ARS + t] = __float2bfloat16(gelu_f(pm));
                float pg = pag[nd] + pbg[q] + tg;
                pg = fmaf(rel, gwr, pg); pg = fmaf(du, gwd, pg); pg = fmaf(ad, gwa, pg);
                float gv = gelu_f(pg) * g2;
                #pragma unroll
                for (int off = 32; off > 0; off >>= 1) gv += __shfl_xor(gv, off);
                if (lane == 0) s_gpart[wv][e] = gv;
            }
        }
    }
    __syncthreads();
    if (t < EEPB) {
        float v = s_gpart[0][t] + s_gpart[1][t] + s_gpart[2][t] + s_gpart[3][t] + gate_b2[0];
        s_gate[t] = 1.f / (1.f + expf(-v));
    } else if (t < EM) {
        s_gate[t] = 0.f;
    }
    // (s_gate consumed after the post-layer2 barrier)

    // ---- layer 2: a2 = gelu(a1 @ w2 + b2)  [MFMA 32x32x16 bf16] ----
    const int cl = lane & 31;   // row (A) / col (B) within 32-tile
    const int g  = lane >> 5;   // k-group
    f32x16 acc00 = zero16(), acc01 = zero16(), acc10 = zero16(), acc11 = zero16();
    {
        const __hip_bfloat16* w2a = w2t + (size_t)((wv*2+0)*32 + cl)*256 + g*8;
        const __hip_bfloat16* w2b = w2t + (size_t)((wv*2+1)*32 + cl)*256 + g*8;
        const __hip_bfloat16* a1a = a1 + (size_t)(0*32 + cl)*ARS + g*8;
        const __hip_bfloat16* a1b = a1 + (size_t)(1*32 + cl)*ARS + g*8;
        #pragma unroll
        for (int kt = 0; kt < 16; ++kt) {
            bf16x8 bfa = *(const bf16x8*)(w2a + kt*16);
            bf16x8 bfb = *(const bf16x8*)(w2b + kt*16);
            bf16x8 afa = *(const bf16x8*)(a1a + kt*16);
            bf16x8 afb = *(const bf16x8*)(a1b + kt*16);
            acc00 = MFMA32(afa, bfa, acc00);
            acc01 = MFMA32(afa, bfb, acc01);
            acc10 = MFMA32(afb, bfa, acc10);
            acc11 = MFMA32(afb, bfb, acc11);
        }
    }
    {   // epilogue -> a2 (disjoint from a1, no barrier needed before writes)
        const int c0 = (wv*2+0)*32 + cl;
        const int c1 = (wv*2+1)*32 + cl;
        float b20 = msg_b2[c0], b21 = msg_b2[c1];
        #pragma unroll
        for (int r = 0; r < 16; ++r) {
            int row0 = (r&3) + 8*(r>>2) + 4*g;
            int row1 = 32 + row0;
            a2[row0*ARS + c0] = __float2bfloat16(gelu_f(acc00[r] + b20));
            a2[row0*ARS + c1] = __float2bfloat16(gelu_f(acc01[r] + b21));
            a2[row1*ARS + c0] = __float2bfloat16(gelu_f(acc10[r] + b20));
            a2[row1*ARS + c1] = __float2bfloat16(gelu_f(acc11[r] + b21));
        }
    }
    __syncthreads();   // a2 complete; all a1 reads done

    // ---- layer 3: msg = (a2 @ w3 + b3) * gate  [MFMA 32x32x16 bf16] ----
    f32x16 m0 = zero16(), m1 = zero16();
    {
        const __hip_bfloat16* w3p = w3t + (size_t)(wv*32 + cl)*256 + g*8;
        const __hip_bfloat16* a2a = a2 + (size_t)(0*32 + cl)*ARS + g*8;
        const __hip_bfloat16* a2b = a2 + (size_t)(1*32 + cl)*ARS + g*8;
        #pragma unroll
        for (int kt = 0; kt < 16; ++kt) {
            bf16x8 bfr = *(const bf16x8*)(w3p + kt*16);
            m0 = MFMA32(*(const bf16x8*)(a2a + kt*16), bfr, m0);
            m1 = MFMA32(*(const bf16x8*)(a2b + kt*16), bfr, m1);
        }
    }
    float* msgbuf = (float*)a1;   // reuse a1 region as [64][MRS] f32
    {
        const int c = wv*32 + cl;
        float b3v = msg_b3[c];
        #pragma unroll
        for (int r = 0; r < 16; ++r) {
            int row0 = (r&3) + 8*(r>>2) + 4*g;
            int row1 = 32 + row0;
            msgbuf[row0*MRS + c] = (m0[r] + b3v) * s_gate[row0];
            msgbuf[row1*MRS + c] = (m1[r] + b3v) * s_gate[row1];
        }
    }
    __syncthreads();

    // ---- aggregate the 7 edges of each node ----
    {
        const int c   = t & 127;
        const int grp = t >> 7;
        #pragma unroll
        for (int p = 0; p < 4; ++p) {
            int nd = grp + p*2;
            float ssum = 0.f;
            #pragma unroll
            for (int q2 = 0; q2 < 7; ++q2) ssum += msgbuf[(nd*7+q2)*MRS + c];
            AGG[(size_t)(base+nd)*128 + c] = ssum;
        }
    }
}

// ---------------- update kernel: u1,u2,u3 + local + final gelu ----------------
#define NTU 8
__global__ __launch_bounds__(256)
void update_kernel(const float* __restrict__ upd_w1,
                   const float* __restrict__ upd_w2, const float* __restrict__ upd_b2,
                   const float* __restrict__ upd_w3, const float* __restrict__ upd_b3,
                   const __hip_bfloat16* __restrict__ HU, const float* __restrict__ HL,
                   const float* __restrict__ AGG, const float* __restrict__ TU,
                   float* __restrict__ out)
{
    __shared__ __align__(16) float aggs[NTU][128];
    __shared__ __align__(16) float U1[NTU][LSTR];
    __shared__ __align__(16) float U2[NTU][LSTR];
    const int t = threadIdx.x;
    const int base = blockIdx.x * NTU;
    const int b = base / NXC;

    for (int idx = t; idx < NTU*128; idx += 256)
        aggs[idx >> 7][idx & 127] = AGG[(size_t)base*128 + idx];
    __syncthreads();

    // u1 = gelu(HU + agg @ upd_w1[128:256] + TU)
    {
        float tu = TU[b*256 + t];
        float acc[NTU];
        #pragma unroll
        for (int nd = 0; nd < NTU; ++nd)
            acc[nd] = tu + __bfloat162float(HU[(size_t)(base+nd)*256 + t]);
        for (int k4 = 0; k4 < 128; k4 += 4) {
            float w0 = upd_w1[(size_t)(128+k4+0)*256+t];
            float w1 = upd_w1[(size_t)(128+k4+1)*256+t];
            float w2 = upd_w1[(size_t)(128+k4+2)*256+t];
            float w3 = upd_w1[(size_t)(128+k4+3)*256+t];
            #pragma unroll
            for (int nd = 0; nd < NTU; ++nd) {
                float4 av = *(const float4*)&aggs[nd][k4];
                acc[nd] = fmaf(av.x, w0, acc[nd]);
                acc[nd] = fmaf(av.y, w1, acc[nd]);
                acc[nd] = fmaf(av.z, w2, acc[nd]);
                acc[nd] = fmaf(av.w, w3, acc[nd]);
            }
        }
        #pragma unroll
        for (int nd = 0; nd < NTU; ++nd) U1[nd][t] = gelu_f(acc[nd]);
    }
    __syncthreads();

    // u2 = gelu(u1 @ upd_w2 + b2)
    {
        float acc[NTU];
        float bb = upd_b2[t];
        #pragma unroll
        for (int nd = 0; nd < NTU; ++nd) acc[nd] = bb;
        for (int k4 = 0; k4 < 256; k4 += 4) {
            float w0 = upd_w2[(size_t)(k4+0)*256+t];
            float w1 = upd_w2[(size_t)(k4+1)*256+t];
            float w2 = upd_w2[(size_t)(k4+2)*256+t];
            float w3 = upd_w2[(size_t)(k4+3)*256+t];
            #pragma unroll
            for (int nd = 0; nd < NTU; ++nd) {
                float4 uv = *(const float4*)&U1[nd][k4];
                acc[nd] = fmaf(uv.x, w0, acc[nd]);
                acc[nd] = fmaf(uv.y, w1, acc[nd]);
                acc[nd] = fmaf(uv.z, w2, acc[nd]);
                acc[nd] = fmaf(uv.w, w3, acc[nd]);
            }
        }
        #pragma unroll
        for (int nd = 0; nd < NTU; ++nd) U2[nd][t] = gelu_f(acc[nd]);
    }
    __syncthreads();

    // u3 + local + gelu
    {
        const int col = t & 127;
        const int h2 = t >> 7;
        float b3 = upd_b3[col];
        float acc[4] = {b3, b3, b3, b3};
        for (int k4 = 0; k4 < 256; k4 += 4) {
            #pragma unroll
            for (int kk = 0; kk < 4; ++kk) {
                float w = upd_w3[(size_t)(k4+kk)*128 + col];
                #pragma unroll
                for (int p = 0; p < 4; ++p)
                    acc[p] = fmaf(U2[h2*4+p][k4+kk], w, acc[p]);
            }
        }
        #pragma unroll
        for (int p = 0; p < 4; ++p) {
            int nd = h2*4 + p;
            size_t o = (size_t)(base+nd)*128 + col;
            out[o] = gelu_f(acc[p] + HL[o]);
        }
    }
}

// ---------------- launch ----------------
extern "C" void kernel_launch(void* const* d_in, const int* in_sizes, int n_in,
                              void* d_out, int out_size, void* d_ws, size_t ws_size,
                              hipStream_t stream)
{
    const float* h      = (const float*)d_in[0];
    const float* x      = (const float*)d_in[1];
    const float* tau    = (const float*)d_in[2];
    const float* u0     = (const float*)d_in[3];
    const float* msg_w1 = (const float*)d_in[4];
    const float* msg_b1 = (const float*)d_in[5];
    const float* msg_w2 = (const float*)d_in[6];
    const float* msg_b2 = (const float*)d_in[7];
    const float* msg_w3 = (const float*)d_in[8];
    const float* msg_b3 = (const float*)d_in[9];
    const float* gate_w1= (const float*)d_in[10];
    const float* gate_b1= (const float*)d_in[11];
    const float* gate_w2= (const float*)d_in[12];
    const float* gate_b2= (const float*)d_in[13];
    const float* upd_w1 = (const float*)d_in[14];
    const float* upd_b1 = (const float*)d_in[15];
    const float* upd_w2 = (const float*)d_in[16];
    const float* upd_b2 = (const float*)d_in[17];
    const float* upd_w3 = (const float*)d_in[18];
    const float* upd_b3 = (const float*)d_in[19];
    const float* W_w    = (const float*)d_in[20];
    const float* W_b    = (const float*)d_in[21];
    float* out = (float*)d_out;

    char* ws = (char*)d_ws;
    size_t off = 0;
    auto alloc = [&](size_t bytes) -> void* {
        void* p = ws + off;
        off += (bytes + 255) & ~(size_t)255;
        return p;
    };
    __hip_bfloat16* PAm = (__hip_bfloat16*)alloc((size_t)NNODES*256*2);
    __hip_bfloat16* PBm = (__hip_bfloat16*)alloc((size_t)NNODES*256*2);
    __hip_bfloat16* PAg = (__hip_bfloat16*)alloc((size_t)NNODES*256*2);
    __hip_bfloat16* PBg = (__hip_bfloat16*)alloc((size_t)NNODES*256*2);
    __hip_bfloat16* HU  = (__hip_bfloat16*)alloc((size_t)NNODES*256*2);
    float* HL  = (float*)alloc((size_t)NNODES*128*4);
    float* AGG = (float*)alloc((size_t)NNODES*128*4);
    float* TM  = (float*)alloc(8*256*4);
    float* TG  = (float*)alloc(8*256*4);
    float* TU  = (float*)alloc(8*256*4);
    __hip_bfloat16* w2t = (__hip_bfloat16*)alloc((size_t)256*256*2);
    __hip_bfloat16* w3t = (__hip_bfloat16*)alloc((size_t)128*256*2);
    (void)ws_size; (void)in_sizes; (void)n_in; (void)out_size;

    tau_kernel<<<8, 256, 0, stream>>>(tau, msg_w1, msg_b1, gate_w1, gate_b1,
                                      upd_w1, upd_b1, TM, TG, TU);
    wconv_kernel<<<256, 256, 0, stream>>>(msg_w2, msg_w3, w2t, w3t);
    precompute_kernel<<<NNODES/16, 256, 0, stream>>>(h, msg_w1, gate_w1, upd_w1,
                                                     W_w, W_b, PAm, PBm, PAg, PBg, HU, HL);
    edge_kernel<<<NNODES/ENPB, 256, 0, stream>>>(x, u0, msg_w1, gate_w1,
                                                 w2t, msg_b2, w3t, msg_b3,
                                                 gate_w2, gate_b2,
                                                 PAm, PBm, PAg, PBg, TM, TG, AGG);
    update_kernel<<<NNODES/NTU, 256, 0, stream>>>(upd_w1, upd_w2, upd_b2, upd_w3, upd_b3,
                                                  HU, HL, AGG, TU, out);
}

// Round 3
// 243.243 us; speedup vs baseline: 13.7802x; 3.0821x over previous
//
#include <hip/hip_runtime.h>
#include <hip/hip_bf16.h>
#include <math.h>

#define NXC 4096
#define NNODES 32768       // B*NX = 8*4096

typedef __attribute__((ext_vector_type(8))) short bf16x8;
typedef __attribute__((ext_vector_type(4))) short s16x4;
typedef __attribute__((ext_vector_type(16))) float f32x16;

#define MFMA32(a,b,c) __builtin_amdgcn_mfma_f32_32x32x16_bf16((a),(b),(c),0,0,0)

// fast tanh-GELU: gelu(v) = v*E/(E+1), E = 2^(c1*v + c2*v^3); max err ~4e-4
__device__ __forceinline__ float gelu_f(float v) {
    float z = v * fmaf(v*v, 0.10294324f, 2.3022082f);
    float e = __builtin_amdgcn_exp2f(z);
    return v - v * __builtin_amdgcn_rcpf(1.0f + e);
}
__device__ __forceinline__ float sigmoid_f(float v) {
    float e = __builtin_amdgcn_exp2f(-1.4426950409f * v);
    return __builtin_amdgcn_rcpf(1.0f + e);
}
__device__ __forceinline__ short f2bs(float x) {
    __hip_bfloat16 b = __float2bfloat16(x);
    union { __hip_bfloat16 h; short s; } u; u.h = b; return u.s;
}
__device__ __forceinline__ f32x16 zero16() {
    f32x16 v;
    #pragma unroll
    for (int i = 0; i < 16; ++i) v[i] = 0.f;
    return v;
}

// ---------------- tau terms (per batch): TM/TG/TU = tau @ W1_tau + b1 ----------------
__global__ void tau_kernel(const float* __restrict__ tau,
                           const float* __restrict__ msg_w1, const float* __restrict__ msg_b1,
                           const float* __restrict__ gate_w1, const float* __restrict__ gate_b1,
                           const float* __restrict__ upd_w1, const float* __restrict__ upd_b1,
                           float* __restrict__ TM, float* __restrict__ TG, float* __restrict__ TU)
{
    const int b = blockIdx.x;      // 0..7
    const int t = threadIdx.x;     // 0..255
    float tv[16];
    #pragma unroll
    for (int k = 0; k < 16; ++k) tv[k] = tau[b*16 + k];
    float am = msg_b1[t], ag = gate_b1[t], au = upd_b1[t];
    #pragma unroll
    for (int k = 0; k < 16; ++k) {
        am = fmaf(tv[k], msg_w1 [(257+k)*256 + t], am);
        ag = fmaf(tv[k], gate_w1[(257+k)*256 + t], ag);
        au = fmaf(tv[k], upd_w1 [(256+k)*256 + t], au);
    }
    TM[b*256+t] = am; TG[b*256+t] = ag; TU[b*256+t] = au;
}

// ---------------- weight prep: all bf16-transposed weight blocks ----------------
// w2t[256][256], w3t[128][256], wall_t[1408][128], w1bt[256][128], w2ut[256][256], w3ut[128][256]
__global__ void wconv_kernel(const float* __restrict__ msg_w2, const float* __restrict__ msg_w3,
                             const float* __restrict__ msg_w1, const float* __restrict__ gate_w1,
                             const float* __restrict__ upd_w1, const float* __restrict__ upd_w2,
                             const float* __restrict__ upd_w3, const float* __restrict__ W_w,
                             __hip_bfloat16* __restrict__ w2t, __hip_bfloat16* __restrict__ w3t,
                             __hip_bfloat16* __restrict__ wall_t, __hip_bfloat16* __restrict__ w1bt,
                             __hip_bfloat16* __restrict__ w2ut, __hip_bfloat16* __restrict__ w3ut)
{
    int i = blockIdx.x * 256 + threadIdx.x;   // 0 .. 409599
    if (i < 65536) { int c=i>>8, k=i&255; w2t[i] = __float2bfloat16(msg_w2[k*256+c]); return; }
    i -= 65536;
    if (i < 32768) { int c=i>>8, k=i&255; w3t[i] = __float2bfloat16(msg_w3[k*128+c]); return; }
    i -= 32768;
    if (i < 180224) {
        int c = i>>7, k = i&127; float v;
        if      (c <  256) v = msg_w1 [k*256 + c];
        else if (c <  512) v = msg_w1 [(128+k)*256 + (c-256)];
        else if (c <  768) v = gate_w1[k*256 + (c-512)];
        else if (c < 1024) v = gate_w1[(128+k)*256 + (c-768)];
        else if (c < 1280) v = upd_w1 [k*256 + (c-1024)];
        else               v = W_w    [k*128 + (c-1280)];
        wall_t[i] = __float2bfloat16(v); return;
    }
    i -= 180224;
    if (i < 32768) { int c=i>>7, k=i&127; w1bt[i] = __float2bfloat16(upd_w1[(128+k)*256+c]); return; }
    i -= 32768;
    if (i < 65536) { int c=i>>8, k=i&255; w2ut[i] = __float2bfloat16(upd_w2[k*256+c]); return; }
    i -= 65536;
    { int c=i>>8, k=i&255; w3ut[i] = __float2bfloat16(upd_w3[k*128+c]); }
}

// ---------------- per-node precompute (MFMA): [PAm|PBm|PAg|PBg|HU|HL] = h @ wall ----------------
#define PSTR 136   // h-tile LDS row stride (bf16), 272 B

__global__ __launch_bounds__(256)
void precompute_kernel(const float* __restrict__ h, const __hip_bfloat16* __restrict__ wall_t,
                       const float* __restrict__ W_b,
                       __hip_bfloat16* __restrict__ PAm, __hip_bfloat16* __restrict__ PBm,
                       __hip_bfloat16* __restrict__ PAg, __hip_bfloat16* __restrict__ PBg,
                       __hip_bfloat16* __restrict__ HU, float* __restrict__ HL)
{
    __shared__ __align__(16) __hip_bfloat16 hs[64*PSTR];
    const int t = threadIdx.x;
    const int lane = t & 63, wv = t >> 6;
    const int cl = lane & 31, g = lane >> 5;
    const int base = blockIdx.x * 64;
    const int tile = blockIdx.y;   // 0..10

    #pragma unroll
    for (int i = 0; i < 8; ++i) {          // stage h tile (64x128 f32 -> bf16)
        int f = (i*256 + t)*4;
        float4 hv = *(const float4*)&h[(size_t)base*128 + f];
        int row = f >> 7, col = f & 127;
        s16x4 pk; pk[0]=f2bs(hv.x); pk[1]=f2bs(hv.y); pk[2]=f2bs(hv.z); pk[3]=f2bs(hv.w);
        *(s16x4*)&hs[row*PSTR + col] = pk;
    }
    __syncthreads();

    f32x16 acc0 = zero16(), acc1 = zero16();
    {
        const __hip_bfloat16* wp  = wall_t + ((size_t)tile*128 + wv*32 + cl)*128 + g*8;
        const __hip_bfloat16* a0  = hs + (size_t)(cl)*PSTR + g*8;
        const __hip_bfloat16* a1p = hs + (size_t)(32+cl)*PSTR + g*8;
        #pragma unroll
        for (int kt = 0; kt < 8; ++kt) {
            bf16x8 bf = *(const bf16x8*)(wp + kt*16);
            acc0 = MFMA32(*(const bf16x8*)(a0  + kt*16), bf, acc0);
            acc1 = MFMA32(*(const bf16x8*)(a1p + kt*16), bf, acc1);
        }
    }
    const int n = tile*128 + wv*32 + cl;
    if (tile < 10) {
        __hip_bfloat16* bufs[5] = {PAm, PBm, PAg, PBg, HU};
        __hip_bfloat16* dst = bufs[n >> 8];
        const int col = n & 255;
        #pragma unroll
        for (int r = 0; r < 16; ++r) {
            int row = (r&3) + 8*(r>>2) + 4*g;
            dst[(size_t)(base+row)*256 + col]    = __float2bfloat16(acc0[r]);
            dst[(size_t)(base+32+row)*256 + col] = __float2bfloat16(acc1[r]);
        }
    } else {
        const int col = n & 127;
        float wb = W_b[col];
        #pragma unroll
        for (int r = 0; r < 16; ++r) {
            int row = (r&3) + 8*(r>>2) + 4*g;
            HL[(size_t)(base+row)*128 + col]    = acc0[r] + wb;
            HL[(size_t)(base+32+row)*128 + col] = acc1[r] + wb;
        }
    }
}

// ---------------- fused edge kernel: layer1(VALU) -> MFMA layer2 -> MFMA layer3 -> agg ----------------
#define ENPB 8     // nodes per block
#define EEPB 56    // edges per block
#define EM   64    // padded M
#define ARS  264   // a1/a2 row stride in bf16 (528 B)
#define MRS  132   // msgbuf row stride in f32 (528 B)
#define GRS  132   // gate-partial row stride in f32 (528 B)

__global__ __launch_bounds__(256, 2)
void edge_kernel(const float* __restrict__ x, const float* __restrict__ u0,
                 const float* __restrict__ msg_w1, const float* __restrict__ gate_w1,
                 const __hip_bfloat16* __restrict__ w2t, const float* __restrict__ msg_b2,
                 const __hip_bfloat16* __restrict__ w3t, const float* __restrict__ msg_b3,
                 const float* __restrict__ gate_w2, const float* __restrict__ gate_b2,
                 const __hip_bfloat16* __restrict__ PAm, const __hip_bfloat16* __restrict__ PBm,
                 const __hip_bfloat16* __restrict__ PAg, const __hip_bfloat16* __restrict__ PBg,
                 const float* __restrict__ TM, const float* __restrict__ TG,
                 float* __restrict__ AGG)
{
    __shared__ __align__(16) __hip_bfloat16 a1[EM*ARS];
    __shared__ __align__(16) __hip_bfloat16 a2[EM*ARS];
    __shared__ float s_rel[EEPB], s_du[EEPB], s_ad[EEPB];
    __shared__ int   s_slotj[14];
    __shared__ float s_gate[EM];

    const int t    = threadIdx.x;
    const int lane = t & 63;
    const int wv   = t >> 6;
    const int base = blockIdx.x * ENPB;
    const int b    = base >> 12;
    const int ii0  = base & (NXC-1);

    if (t < 14) {
        int jj = ii0 - 3 + t;
        jj = jj < 0 ? 0 : (jj > NXC-1 ? NXC-1 : jj);
        s_slotj[t] = b*NXC + jj;
    }
    if (t < EEPB) {
        int nd = t / 7, s = t - nd*7;
        int i  = base + nd;
        int jj = ii0 + nd + s - 3;
        jj = jj < 0 ? 0 : (jj > NXC-1 ? NXC-1 : jj);
        int j = b*NXC + jj;
        float rel = x[j] - x[i];
        float du  = u0[i] - u0[j];
        s_rel[t] = rel; s_du[t] = du; s_ad[t] = fabsf(du);
    }
    {   // zero a1 pad rows 56..63 (data region)
        int r = 56 + (t >> 5);
        float4 z = {0.f, 0.f, 0.f, 0.f};
        *(float4*)((char*)a1 + (size_t)r*528 + (size_t)(t & 31)*16) = z;
    }
    __syncthreads();

    // ---- phase 1: decomposed layer-1; msg gelu -> a1; gate gelu*w2 -> gbuf (a2 region) ----
    float* gbuf = (float*)a2;
    {
        float wr  = msg_w1 [256*256+t], wd  = msg_w1 [273*256+t], wa  = msg_w1 [274*256+t];
        float gwr = gate_w1[256*256+t], gwd = gate_w1[273*256+t], gwa = gate_w1[274*256+t];
        float tm = TM[b*256+t], tg = TG[b*256+t];
        float g2 = gate_w2[t];
        float pbm[14], pbg[14], pam[8], pag[8];
        #pragma unroll
        for (int q = 0; q < 14; ++q) {
            size_t o = (size_t)s_slotj[q]*256 + t;
            pbm[q] = __bfloat162float(PBm[o]);
            pbg[q] = __bfloat162float(PBg[o]);
        }
        #pragma unroll
        for (int nd = 0; nd < 8; ++nd) {
            size_t o = (size_t)(base+nd)*256 + t;
            pam[nd] = __bfloat162float(PAm[o]);
            pag[nd] = __bfloat162float(PAg[o]);
        }
        #pragma unroll
        for (int nd = 0; nd < 8; ++nd) {
            #pragma unroll
            for (int s = 0; s < 7; ++s) {
                const int e = nd*7 + s, q = nd + s;
                float rel = s_rel[e], du = s_du[e], ad = s_ad[e];
                float pm = pam[nd] + pbm[q] + tm;
                pm = fmaf(rel, wr, pm); pm = fmaf(du, wd, pm); pm = fmaf(ad, wa, pm);
                a1[e*ARS + t] = __float2bfloat16(gelu_f(pm));
                float pg = pag[nd] + pbg[q] + tg;
                pg = fmaf(rel, gwr, pg); pg = fmaf(du, gwd, pg); pg = fmaf(ad, gwa, pg);
                gbuf[e*GRS + t] = gelu_f(pg) * g2;
            }
        }
    }
    __syncthreads();

    // ---- gate reduce: wave wv reduces edges wv*14 .. wv*14+13 ----
    if (t >= EEPB && t < EM) s_gate[t] = 0.f;
    {
        const float gb2 = gate_b2[0];
        #pragma unroll
        for (int q = 0; q < 14; ++q) {
            int e = wv*14 + q;
            const float* gp = gbuf + e*GRS;
            float v = gp[lane] + gp[lane+64] + gp[lane+128] + gp[lane+192];
            #pragma unroll
            for (int off = 32; off > 0; off >>= 1) v += __shfl_xor(v, off);
            if (lane == 0) s_gate[e] = sigmoid_f(v + gb2);
        }
    }

    // ---- layer 2: a2 = gelu(a1 @ w2 + b2)  [MFMA 32x32x16 bf16] ----
    const int cl = lane & 31;
    const int g  = lane >> 5;
    f32x16 acc00 = zero16(), acc01 = zero16(), acc10 = zero16(), acc11 = zero16();
    {
        const __hip_bfloat16* w2a = w2t + (size_t)((wv*2+0)*32 + cl)*256 + g*8;
        const __hip_bfloat16* w2b = w2t + (size_t)((wv*2+1)*32 + cl)*256 + g*8;
        const __hip_bfloat16* a1a = a1 + (size_t)(0*32 + cl)*ARS + g*8;
        const __hip_bfloat16* a1b = a1 + (size_t)(1*32 + cl)*ARS + g*8;
        #pragma unroll
        for (int kt = 0; kt < 16; ++kt) {
            bf16x8 bfa = *(const bf16x8*)(w2a + kt*16);
            bf16x8 bfb = *(const bf16x8*)(w2b + kt*16);
            bf16x8 afa = *(const bf16x8*)(a1a + kt*16);
            bf16x8 afb = *(const bf16x8*)(a1b + kt*16);
            acc00 = MFMA32(afa, bfa, acc00);
            acc01 = MFMA32(afa, bfb, acc01);
            acc10 = MFMA32(afb, bfa, acc10);
            acc11 = MFMA32(afb, bfb, acc11);
        }
    }
    __syncthreads();   // gbuf reads done before a2 overwrite; s_gate visible
    {
        const int c0 = (wv*2+0)*32 + cl;
        const int c1 = (wv*2+1)*32 + cl;
        float b20 = msg_b2[c0], b21 = msg_b2[c1];
        #pragma unroll
        for (int r = 0; r < 16; ++r) {
            int row0 = (r&3) + 8*(r>>2) + 4*g;
            int row1 = 32 + row0;
            a2[row0*ARS + c0] = __float2bfloat16(gelu_f(acc00[r] + b20));
            a2[row0*ARS + c1] = __float2bfloat16(gelu_f(acc01[r] + b21));
            a2[row1*ARS + c0] = __float2bfloat16(gelu_f(acc10[r] + b20));
            a2[row1*ARS + c1] = __float2bfloat16(gelu_f(acc11[r] + b21));
        }
    }
    __syncthreads();   // a2 complete; all a1 reads done

    // ---- layer 3: msg = (a2 @ w3 + b3) * gate  [MFMA 32x32x16 bf16] ----
    f32x16 m0 = zero16(), m1 = zero16();
    {
        const __hip_bfloat16* w3p = w3t + (size_t)(wv*32 + cl)*256 + g*8;
        const __hip_bfloat16* a2a = a2 + (size_t)(0*32 + cl)*ARS + g*8;
        const __hip_bfloat16* a2b = a2 + (size_t)(1*32 + cl)*ARS + g*8;
        #pragma unroll
        for (int kt = 0; kt < 16; ++kt) {
            bf16x8 bfr = *(const bf16x8*)(w3p + kt*16);
            m0 = MFMA32(*(const bf16x8*)(a2a + kt*16), bfr, m0);
            m1 = MFMA32(*(const bf16x8*)(a2b + kt*16), bfr, m1);
        }
    }
    float* msgbuf = (float*)a1;   // reuse a1 region as [64][MRS] f32
    {
        const int c = wv*32 + cl;
        float b3v = msg_b3[c];
        #pragma unroll
        for (int r = 0; r < 16; ++r) {
            int row0 = (r&3) + 8*(r>>2) + 4*g;
            int row1 = 32 + row0;
            msgbuf[row0*MRS + c] = (m0[r] + b3v) * s_gate[row0];
            msgbuf[row1*MRS + c] = (m1[r] + b3v) * s_gate[row1];
        }
    }
    __syncthreads();

    // ---- aggregate the 7 edges of each node ----
    {
        const int c   = t & 127;
        const int grp = t >> 7;
        #pragma unroll
        for (int p = 0; p < 4; ++p) {
            int nd = grp + p*2;
            float ssum = 0.f;
            #pragma unroll
            for (int q2 = 0; q2 < 7; ++q2) ssum += msgbuf[(nd*7+q2)*MRS + c];
            AGG[(size_t)(base+nd)*128 + c] = ssum;
        }
    }
}

// ---------------- update kernel (MFMA): u1,u2,u3 + local + final gelu ----------------
#define USTR 136

__global__ __launch_bounds__(256, 2)
void update_kernel(const __hip_bfloat16* __restrict__ w1bt, const __hip_bfloat16* __restrict__ w2ut,
                   const __hip_bfloat16* __restrict__ w3ut,
                   const float* __restrict__ upd_b2, const float* __restrict__ upd_b3,
                   const __hip_bfloat16* __restrict__ HU, const float* __restrict__ HL,
                   const float* __restrict__ AGG, const float* __restrict__ TU,
                   float* __restrict__ out)
{
    __shared__ __align__(16) __hip_bfloat16 bufA[EM*ARS];
    __shared__ __align__(16) __hip_bfloat16 bufB[EM*ARS];
    const int t = threadIdx.x;
    const int lane = t & 63, wv = t >> 6;
    const int cl = lane & 31, g = lane >> 5;
    const int base = blockIdx.x * 64;
    const int b = base >> 12;

    #pragma unroll
    for (int i = 0; i < 8; ++i) {          // stage AGG tile (64x128 f32 -> bf16, stride USTR)
        int f = (i*256 + t)*4;
        float4 av = *(const float4*)&AGG[(size_t)base*128 + f];
        int row = f >> 7, col = f & 127;
        s16x4 pk; pk[0]=f2bs(av.x); pk[1]=f2bs(av.y); pk[2]=f2bs(av.z); pk[3]=f2bs(av.w);
        *(s16x4*)&bufA[row*USTR + col] = pk;
    }
    __syncthreads();

    // ---- u1 = gelu(HU + TU + agg @ w1b)  K=128, N=256 ----
    f32x16 u00 = zero16(), u01 = zero16(), u10 = zero16(), u11 = zero16();
    {
        const __hip_bfloat16* a0 = bufA + (size_t)(cl)*USTR + g*8;
        const __hip_bfloat16* a1p = bufA + (size_t)(32+cl)*USTR + g*8;
        const __hip_bfloat16* b0 = w1bt + (size_t)(wv*64 + cl)*128 + g*8;
        const __hip_bfloat16* b1 = w1bt + (size_t)(wv*64 + 32 + cl)*128 + g*8;
        #pragma unroll
        for (int kt = 0; kt < 8; ++kt) {
            bf16x8 bf0 = *(const bf16x8*)(b0 + kt*16);
            bf16x8 bf1 = *(const bf16x8*)(b1 + kt*16);
            bf16x8 af0 = *(const bf16x8*)(a0 + kt*16);
            bf16x8 af1 = *(const bf16x8*)(a1p + kt*16);
            u00 = MFMA32(af0, bf0, u00);
            u01 = MFMA32(af0, bf1, u01);
            u10 = MFMA32(af1, bf0, u10);
            u11 = MFMA32(af1, bf1, u11);
        }
    }
    {
        const int c0 = wv*64 + cl, c1 = c0 + 32;
        float tu0 = TU[b*256 + c0], tu1 = TU[b*256 + c1];
        #pragma unroll
        for (int r = 0; r < 16; ++r) {
            int row = (r&3) + 8*(r>>2) + 4*g;
            int n0 = base + row, n1 = base + 32 + row;
            bufB[row*ARS + c0]      = __float2bfloat16(gelu_f(u00[r] + tu0 + __bfloat162float(HU[(size_t)n0*256 + c0])));
            bufB[row*ARS + c1]      = __float2bfloat16(gelu_f(u01[r] + tu1 + __bfloat162float(HU[(size_t)n0*256 + c1])));
            bufB[(32+row)*ARS + c0] = __float2bfloat16(gelu_f(u10[r] + tu0 + __bfloat162float(HU[(size_t)n1*256 + c0])));
            bufB[(32+row)*ARS + c1] = __float2bfloat16(gelu_f(u11[r] + tu1 + __bfloat162float(HU[(size_t)n1*256 + c1])));
        }
    }
    __syncthreads();

    // ---- u2 = gelu(u1 @ w2u + b2)  K=256, N=256 ----
    f32x16 v00 = zero16(), v01 = zero16(), v10 = zero16(), v11 = zero16();
    {
        const __hip_bfloat16* a0 = bufB + (size_t)(cl)*ARS + g*8;
        const __hip_bfloat16* a1p = bufB + (size_t)(32+cl)*ARS + g*8;
        const __hip_bfloat16* b0 = w2ut + (size_t)(wv*64 + cl)*256 + g*8;
        const __hip_bfloat16* b1 = w2ut + (size_t)(wv*64 + 32 + cl)*256 + g*8;
        #pragma unroll
        for (int kt = 0; kt < 16; ++kt) {
            bf16x8 bf0 = *(const bf16x8*)(b0 + kt*16);
            bf16x8 bf1 = *(const bf16x8*)(b1 + kt*16);
            bf16x8 af0 = *(const bf16x8*)(a0 + kt*16);
            bf16x8 af1 = *(const bf16x8*)(a1p + kt*16);
            v00 = MFMA32(af0, bf0, v00);
            v01 = MFMA32(af0, bf1, v01);
            v10 = MFMA32(af1, bf0, v10);
            v11 = MFMA32(af1, bf1, v11);
        }
    }
    {
        const int c0 = wv*64 + cl, c1 = c0 + 32;
        float b20 = upd_b2[c0], b21 = upd_b2[c1];
        #pragma unroll
        for (int r = 0; r < 16; ++r) {
            int row = (r&3) + 8*(r>>2) + 4*g;
            bufA[row*ARS + c0]      = __float2bfloat16(gelu_f(v00[r] + b20));
            bufA[row*ARS + c1]      = __float2bfloat16(gelu_f(v01[r] + b21));
            bufA[(32+row)*ARS + c0] = __float2bfloat16(gelu_f(v10[r] + b20));
            bufA[(32+row)*ARS + c1] = __float2bfloat16(gelu_f(v11[r] + b21));
        }
    }
    __syncthreads();

    // ---- out = gelu(u2 @ w3u + b3 + HL)  K=256, N=128 ----
    f32x16 w0 = zero16(), w1 = zero16();
    {
        const __hip_bfloat16* wp = w3ut + (size_t)(wv*32 + cl)*256 + g*8;
        const __hip_bfloat16* a0 = bufA + (size_t)(cl)*ARS + g*8;
        const __hip_bfloat16* a1p = bufA + (size_t)(32+cl)*ARS + g*8;
        #pragma unroll
        for (int kt = 0; kt < 16; ++kt) {
            bf16x8 bfr = *(const bf16x8*)(wp + kt*16);
            w0 = MFMA32(*(const bf16x8*)(a0 + kt*16), bfr, w0);
            w1 = MFMA32(*(const bf16x8*)(a1p + kt*16), bfr, w1);
        }
    }
    {
        const int c = wv*32 + cl;
        float b3v = upd_b3[c];
        #pragma unroll
        for (int r = 0; r < 16; ++r) {
            int row = (r&3) + 8*(r>>2) + 4*g;
            size_t o0 = (size_t)(base+row)*128 + c;
            size_t o1 = (size_t)(base+32+row)*128 + c;
            out[o0] = gelu_f(w0[r] + b3v + HL[o0]);
            out[o1] = gelu_f(w1[r] + b3v + HL[o1]);
        }
    }
}

// ---------------- launch ----------------
extern "C" void kernel_launch(void* const* d_in, const int* in_sizes, int n_in,
                              void* d_out, int out_size, void* d_ws, size_t ws_size,
                              hipStream_t stream)
{
    const float* h      = (const float*)d_in[0];
    const float* x      = (const float*)d_in[1];
    const float* tau    = (const float*)d_in[2];
    const float* u0     = (const float*)d_in[3];
    const float* msg_w1 = (const float*)d_in[4];
    const float* msg_b1 = (const float*)d_in[5];
    const float* msg_w2 = (const float*)d_in[6];
    const float* msg_b2 = (const float*)d_in[7];
    const float* msg_w3 = (const float*)d_in[8];
    const float* msg_b3 = (const float*)d_in[9];
    const float* gate_w1= (const float*)d_in[10];
    const float* gate_b1= (const float*)d_in[11];
    const float* gate_w2= (const float*)d_in[12];
    const float* gate_b2= (const float*)d_in[13];
    const float* upd_w1 = (const float*)d_in[14];
    const float* upd_b1 = (const float*)d_in[15];
    const float* upd_w2 = (const float*)d_in[16];
    const float* upd_b2 = (const float*)d_in[17];
    const float* upd_w3 = (const float*)d_in[18];
    const float* upd_b3 = (const float*)d_in[19];
    const float* W_w    = (const float*)d_in[20];
    const float* W_b    = (const float*)d_in[21];
    float* out = (float*)d_out;

    char* ws = (char*)d_ws;
    size_t off = 0;
    auto alloc = [&](size_t bytes) -> void* {
        void* p = ws + off;
        off += (bytes + 255) & ~(size_t)255;
        return p;
    };
    __hip_bfloat16* PAm = (__hip_bfloat16*)alloc((size_t)NNODES*256*2);
    __hip_bfloat16* PBm = (__hip_bfloat16*)alloc((size_t)NNODES*256*2);
    __hip_bfloat16* PAg = (__hip_bfloat16*)alloc((size_t)NNODES*256*2);
    __hip_bfloat16* PBg = (__hip_bfloat16*)alloc((size_t)NNODES*256*2);
    __hip_bfloat16* HU  = (__hip_bfloat16*)alloc((size_t)NNODES*256*2);
    float* HL  = (float*)alloc((size_t)NNODES*128*4);
    float* AGG = (float*)alloc((size_t)NNODES*128*4);
    float* TM  = (float*)alloc(8*256*4);
    float* TG  = (float*)alloc(8*256*4);
    float* TU  = (float*)alloc(8*256*4);
    __hip_bfloat16* w2t   = (__hip_bfloat16*)alloc((size_t)256*256*2);
    __hip_bfloat16* w3t   = (__hip_bfloat16*)alloc((size_t)128*256*2);
    __hip_bfloat16* wall_t= (__hip_bfloat16*)alloc((size_t)1408*128*2);
    __hip_bfloat16* w1bt  = (__hip_bfloat16*)alloc((size_t)256*128*2);
    __hip_bfloat16* w2ut  = (__hip_bfloat16*)alloc((size_t)256*256*2);
    __hip_bfloat16* w3ut  = (__hip_bfloat16*)alloc((size_t)128*256*2);
    (void)ws_size; (void)in_sizes; (void)n_in; (void)out_size;

    tau_kernel<<<8, 256, 0, stream>>>(tau, msg_w1, msg_b1, gate_w1, gate_b1,
                                      upd_w1, upd_b1, TM, TG, TU);
    wconv_kernel<<<1600, 256, 0, stream>>>(msg_w2, msg_w3, msg_w1, gate_w1,
                                           upd_w1, upd_w2, upd_w3, W_w,
                                           w2t, w3t, wall_t, w1bt, w2ut, w3ut);
    precompute_kernel<<<dim3(NNODES/64, 11), 256, 0, stream>>>(h, wall_t, W_b,
                                                               PAm, PBm, PAg, PBg, HU, HL);
    edge_kernel<<<NNODES/ENPB, 256, 0, stream>>>(x, u0, msg_w1, gate_w1,
                                                 w2t, msg_b2, w3t, msg_b3,
                                                 gate_w2, gate_b2,
                                                 PAm, PBm, PAg, PBg, TM, TG, AGG);
    update_kernel<<<NNODES/64, 256, 0, stream>>>(w1bt, w2ut, w3ut, upd_b2, upd_b3,
                                                 HU, HL, AGG, TU, out);
}

// Round 4
// 240.561 us; speedup vs baseline: 13.9338x; 1.0111x over previous
//
#include <hip/hip_runtime.h>
#include <hip/hip_bf16.h>
#include <math.h>

#define NXC 4096
#define NNODES 32768       // B*NX = 8*4096

typedef __attribute__((ext_vector_type(8))) short bf16x8;
typedef __attribute__((ext_vector_type(4))) short s16x4;
typedef __attribute__((ext_vector_type(16))) float f32x16;

#define MFMA32(a,b,c) __builtin_amdgcn_mfma_f32_32x32x16_bf16((a),(b),(c),0,0,0)

// fast tanh-GELU: gelu(v) = v - v/(1+E), E = 2^(c1*v + c2*v^3); max err ~4e-4
__device__ __forceinline__ float gelu_f(float v) {
    float z = v * fmaf(v*v, 0.10294324f, 2.3022082f);
    float e = __builtin_amdgcn_exp2f(z);
    return v - v * __builtin_amdgcn_rcpf(1.0f + e);
}
__device__ __forceinline__ float sigmoid_f(float v) {
    float e = __builtin_amdgcn_exp2f(-1.4426950409f * v);
    return __builtin_amdgcn_rcpf(1.0f + e);
}
__device__ __forceinline__ short f2bs(float x) {
    __hip_bfloat16 b = __float2bfloat16(x);
    union { __hip_bfloat16 h; short s; } u; u.h = b; return u.s;
}
__device__ __forceinline__ f32x16 zero16() {
    f32x16 v;
    #pragma unroll
    for (int i = 0; i < 16; ++i) v[i] = 0.f;
    return v;
}

// ---------------- tau terms (per batch): TM/TG/TU = tau @ W1_tau + b1 ----------------
__global__ void tau_kernel(const float* __restrict__ tau,
                           const float* __restrict__ msg_w1, const float* __restrict__ msg_b1,
                           const float* __restrict__ gate_w1, const float* __restrict__ gate_b1,
                           const float* __restrict__ upd_w1, const float* __restrict__ upd_b1,
                           float* __restrict__ TM, float* __restrict__ TG, float* __restrict__ TU)
{
    const int b = blockIdx.x;      // 0..7
    const int t = threadIdx.x;     // 0..255
    float tv[16];
    #pragma unroll
    for (int k = 0; k < 16; ++k) tv[k] = tau[b*16 + k];
    float am = msg_b1[t], ag = gate_b1[t], au = upd_b1[t];
    #pragma unroll
    for (int k = 0; k < 16; ++k) {
        am = fmaf(tv[k], msg_w1 [(257+k)*256 + t], am);
        ag = fmaf(tv[k], gate_w1[(257+k)*256 + t], ag);
        au = fmaf(tv[k], upd_w1 [(256+k)*256 + t], au);
    }
    TM[b*256+t] = am; TG[b*256+t] = ag; TU[b*256+t] = au;
}

// ---------------- weight prep: all bf16-transposed weight blocks ----------------
__global__ void wconv_kernel(const float* __restrict__ msg_w2, const float* __restrict__ msg_w3,
                             const float* __restrict__ msg_w1, const float* __restrict__ gate_w1,
                             const float* __restrict__ upd_w1, const float* __restrict__ upd_w2,
                             const float* __restrict__ upd_w3, const float* __restrict__ W_w,
                             __hip_bfloat16* __restrict__ w2t, __hip_bfloat16* __restrict__ w3t,
                             __hip_bfloat16* __restrict__ wall_t, __hip_bfloat16* __restrict__ w1bt,
                             __hip_bfloat16* __restrict__ w2ut, __hip_bfloat16* __restrict__ w3ut)
{
    int i = blockIdx.x * 256 + threadIdx.x;   // 0 .. 409599
    if (i < 65536) { int c=i>>8, k=i&255; w2t[i] = __float2bfloat16(msg_w2[k*256+c]); return; }
    i -= 65536;
    if (i < 32768) { int c=i>>8, k=i&255; w3t[i] = __float2bfloat16(msg_w3[k*128+c]); return; }
    i -= 32768;
    if (i < 180224) {
        int c = i>>7, k = i&127; float v;
        if      (c <  256) v = msg_w1 [k*256 + c];
        else if (c <  512) v = msg_w1 [(128+k)*256 + (c-256)];
        else if (c <  768) v = gate_w1[k*256 + (c-512)];
        else if (c < 1024) v = gate_w1[(128+k)*256 + (c-768)];
        else if (c < 1280) v = upd_w1 [k*256 + (c-1024)];
        else               v = W_w    [k*128 + (c-1280)];
        wall_t[i] = __float2bfloat16(v); return;
    }
    i -= 180224;
    if (i < 32768) { int c=i>>7, k=i&127; w1bt[i] = __float2bfloat16(upd_w1[(128+k)*256+c]); return; }
    i -= 32768;
    if (i < 65536) { int c=i>>8, k=i&255; w2ut[i] = __float2bfloat16(upd_w2[k*256+c]); return; }
    i -= 65536;
    { int c=i>>8, k=i&255; w3ut[i] = __float2bfloat16(upd_w3[k*128+c]); }
}

// ---------------- per-node precompute (MFMA): [PAm|PBm|PAg|PBg|HU|HL] = h @ wall ----------------
#define PSTR 136   // h-tile LDS row stride (bf16), 272 B

__global__ __launch_bounds__(256, 4)
void precompute_kernel(const float* __restrict__ h, const __hip_bfloat16* __restrict__ wall_t,
                       const float* __restrict__ W_b,
                       __hip_bfloat16* __restrict__ PAm, __hip_bfloat16* __restrict__ PBm,
                       __hip_bfloat16* __restrict__ PAg, __hip_bfloat16* __restrict__ PBg,
                       __hip_bfloat16* __restrict__ HU, float* __restrict__ HL)
{
    __shared__ __align__(16) __hip_bfloat16 hs[64*PSTR];
    const int t = threadIdx.x;
    const int lane = t & 63, wv = t >> 6;
    const int cl = lane & 31, g = lane >> 5;
    const int base = blockIdx.x * 64;
    const int tile = blockIdx.y;   // 0..10

    #pragma unroll
    for (int i = 0; i < 8; ++i) {          // stage h tile (64x128 f32 -> bf16)
        int f = (i*256 + t)*4;
        float4 hv = *(const float4*)&h[(size_t)base*128 + f];
        int row = f >> 7, col = f & 127;
        s16x4 pk; pk[0]=f2bs(hv.x); pk[1]=f2bs(hv.y); pk[2]=f2bs(hv.z); pk[3]=f2bs(hv.w);
        *(s16x4*)&hs[row*PSTR + col] = pk;
    }
    __syncthreads();

    f32x16 acc0 = zero16(), acc1 = zero16();
    {
        const __hip_bfloat16* wp  = wall_t + ((size_t)tile*128 + wv*32 + cl)*128 + g*8;
        const __hip_bfloat16* a0  = hs + (size_t)(cl)*PSTR + g*8;
        const __hip_bfloat16* a1p = hs + (size_t)(32+cl)*PSTR + g*8;
        #pragma unroll
        for (int kt = 0; kt < 8; ++kt) {
            bf16x8 bf = *(const bf16x8*)(wp + kt*16);
            acc0 = MFMA32(*(const bf16x8*)(a0  + kt*16), bf, acc0);
            acc1 = MFMA32(*(const bf16x8*)(a1p + kt*16), bf, acc1);
        }
    }
    if (tile < 10) {
        // stage C tile in LDS (reuse hs), then coalesced float4 stores
        __syncthreads();                       // all hs reads done
        __hip_bfloat16* ob = hs;               // layout [64][128]
        const int ncol = wv*32 + cl;           // 0..127
        #pragma unroll
        for (int r = 0; r < 16; ++r) {
            int row = (r&3) + 8*(r>>2) + 4*g;
            ob[row*128 + ncol]      = __float2bfloat16(acc0[r]);
            ob[(32+row)*128 + ncol] = __float2bfloat16(acc1[r]);
        }
        __syncthreads();
        __hip_bfloat16* bufs[5] = {PAm, PBm, PAg, PBg, HU};
        __hip_bfloat16* dst = bufs[tile >> 1];
        const int coloff = (tile & 1) * 128;
        #pragma unroll
        for (int i = 0; i < 4; ++i) {
            int idx = i*256 + t;               // 0..1023 : 64 rows x 16 chunks of 8 bf16
            int row = idx >> 4, ch = idx & 15;
            *(float4*)&dst[(size_t)(base+row)*256 + coloff + ch*8] =
                *(const float4*)&ob[row*128 + ch*8];
        }
    } else {
        const int col = (wv*32 + cl) & 127;
        float wb = W_b[col];
        #pragma unroll
        for (int r = 0; r < 16; ++r) {
            int row = (r&3) + 8*(r>>2) + 4*g;
            HL[(size_t)(base+row)*128 + col]    = acc0[r] + wb;
            HL[(size_t)(base+32+row)*128 + col] = acc1[r] + wb;
        }
    }
}

// ---------------- fused edge kernel: layer1(VALU) -> MFMA layer2 -> MFMA layer3 -> agg ----------------
#define ENPB 8     // nodes per block
#define EEPB 56    // edges per block
#define ARS  264   // activation row stride in bf16 (528 B, odd multiple of 16 B)
#define MRS  132   // msgbuf row stride in f32 (528 B)

__global__ __launch_bounds__(256, 4)
void edge_kernel(const float* __restrict__ x, const float* __restrict__ u0,
                 const float* __restrict__ msg_w1, const float* __restrict__ gate_w1,
                 const __hip_bfloat16* __restrict__ w2t, const float* __restrict__ msg_b2,
                 const __hip_bfloat16* __restrict__ w3t, const float* __restrict__ msg_b3,
                 const float* __restrict__ gate_w2, const float* __restrict__ gate_b2,
                 const __hip_bfloat16* __restrict__ PAm, const __hip_bfloat16* __restrict__ PBm,
                 const __hip_bfloat16* __restrict__ PAg, const __hip_bfloat16* __restrict__ PBg,
                 const float* __restrict__ TM, const float* __restrict__ TG,
                 float* __restrict__ AGG)
{
    __shared__ __align__(16) __hip_bfloat16 act[64*ARS];   // a1 -> a2 -> msgbuf(f32)
    __shared__ float s_gp[4][EEPB];
    __shared__ float s_rel[EEPB], s_du[EEPB], s_ad[EEPB];
    __shared__ int   s_slotj[14];
    __shared__ float s_gate[EEPB];

    const int t    = threadIdx.x;
    const int lane = t & 63;
    const int wv   = t >> 6;
    const int base = blockIdx.x * ENPB;
    const int b    = base >> 12;
    const int ii0  = base & (NXC-1);

    if (t < 14) {
        int jj = ii0 - 3 + t;
        jj = jj < 0 ? 0 : (jj > NXC-1 ? NXC-1 : jj);
        s_slotj[t] = b*NXC + jj;
    }
    if (t < EEPB) {
        int nd = t / 7, s = t - nd*7;
        int i  = base + nd;
        int jj = ii0 + nd + s - 3;
        jj = jj < 0 ? 0 : (jj > NXC-1 ? NXC-1 : jj);
        int j = b*NXC + jj;
        float rel = x[j] - x[i];
        float du  = u0[i] - u0[j];
        s_rel[t] = rel; s_du[t] = du; s_ad[t] = fabsf(du);
    }
    __syncthreads();

    // ---- phase 1: decomposed layer-1; msg gelu -> act; gate reduced via wave shuffles ----
    {
        float wr  = msg_w1 [256*256+t], wd  = msg_w1 [273*256+t], wa  = msg_w1 [274*256+t];
        float gwr = gate_w1[256*256+t], gwd = gate_w1[273*256+t], gwa = gate_w1[274*256+t];
        float tm = TM[b*256+t], tg = TG[b*256+t];
        float g2 = gate_w2[t];
        float bm[14], bg[14], pam[8], pag[8];
        #pragma unroll
        for (int q = 0; q < 14; ++q) {
            size_t o = (size_t)s_slotj[q]*256 + t;
            bm[q] = __bfloat162float(PBm[o]) + tm;
            bg[q] = __bfloat162float(PBg[o]) + tg;
        }
        #pragma unroll
        for (int nd = 0; nd < 8; ++nd) {
            size_t o = (size_t)(base+nd)*256 + t;
            pam[nd] = __bfloat162float(PAm[o]);
            pag[nd] = __bfloat162float(PAg[o]);
        }
        #pragma unroll
        for (int nd = 0; nd < 8; ++nd) {
            #pragma unroll
            for (int s = 0; s < 7; ++s) {
                const int e = nd*7 + s, q = nd + s;
                float rel = s_rel[e], du = s_du[e], ad = s_ad[e];
                float pm = pam[nd] + bm[q];
                pm = fmaf(rel, wr, pm); pm = fmaf(du, wd, pm); pm = fmaf(ad, wa, pm);
                act[e*ARS + t] = __float2bfloat16(gelu_f(pm));
                float pg = pag[nd] + bg[q];
                pg = fmaf(rel, gwr, pg); pg = fmaf(du, gwd, pg); pg = fmaf(ad, gwa, pg);
                float gv = gelu_f(pg) * g2;
                #pragma unroll
                for (int off = 32; off > 0; off >>= 1) gv += __shfl_xor(gv, off);
                if (lane == 0) s_gp[wv][e] = gv;
            }
        }
    }
    __syncthreads();
    if (t < EEPB)
        s_gate[t] = sigmoid_f(s_gp[0][t] + s_gp[1][t] + s_gp[2][t] + s_gp[3][t] + gate_b2[0]);
    // (s_gate consumed after later barriers)

    // ---- layer 2: a2 = gelu(a1 @ w2 + b2)  [MFMA 32x32x16 bf16] ----
    const int cl = lane & 31;
    const int g  = lane >> 5;
    f32x16 acc00 = zero16(), acc01 = zero16(), acc10 = zero16(), acc11 = zero16();
    {
        const __hip_bfloat16* w2a = w2t + (size_t)((wv*2+0)*32 + cl)*256 + g*8;
        const __hip_bfloat16* w2b = w2t + (size_t)((wv*2+1)*32 + cl)*256 + g*8;
        const __hip_bfloat16* a1a = act + (size_t)(cl)*ARS + g*8;
        const __hip_bfloat16* a1b = act + (size_t)(32+cl)*ARS + g*8;
        #pragma unroll
        for (int kt = 0; kt < 16; ++kt) {
            bf16x8 bfa = *(const bf16x8*)(w2a + kt*16);
            bf16x8 bfb = *(const bf16x8*)(w2b + kt*16);
            bf16x8 afa = *(const bf16x8*)(a1a + kt*16);
            bf16x8 afb = *(const bf16x8*)(a1b + kt*16);
            acc00 = MFMA32(afa, bfa, acc00);
            acc01 = MFMA32(afa, bfb, acc01);
            acc10 = MFMA32(afb, bfa, acc10);
            acc11 = MFMA32(afb, bfb, acc11);
        }
    }
    __syncthreads();   // all a1 reads done -> safe to overwrite act with a2
    {
        const int c0 = (wv*2+0)*32 + cl;
        const int c1 = (wv*2+1)*32 + cl;
        float b20 = msg_b2[c0], b21 = msg_b2[c1];
        #pragma unroll
        for (int r = 0; r < 16; ++r) {
            int row0 = (r&3) + 8*(r>>2) + 4*g;
            int row1 = 32 + row0;
            act[row0*ARS + c0] = __float2bfloat16(gelu_f(acc00[r] + b20));
            act[row0*ARS + c1] = __float2bfloat16(gelu_f(acc01[r] + b21));
            act[row1*ARS + c0] = __float2bfloat16(gelu_f(acc10[r] + b20));
            act[row1*ARS + c1] = __float2bfloat16(gelu_f(acc11[r] + b21));
        }
    }
    __syncthreads();   // a2 complete

    // ---- layer 3: msg = (a2 @ w3 + b3) * gate  [MFMA 32x32x16 bf16] ----
    f32x16 m0 = zero16(), m1 = zero16();
    {
        const __hip_bfloat16* w3p = w3t + (size_t)(wv*32 + cl)*256 + g*8;
        const __hip_bfloat16* a2a = act + (size_t)(cl)*ARS + g*8;
        const __hip_bfloat16* a2b = act + (size_t)(32+cl)*ARS + g*8;
        #pragma unroll
        for (int kt = 0; kt < 16; ++kt) {
            bf16x8 bfr = *(const bf16x8*)(w3p + kt*16);
            m0 = MFMA32(*(const bf16x8*)(a2a + kt*16), bfr, m0);
            m1 = MFMA32(*(const bf16x8*)(a2b + kt*16), bfr, m1);
        }
    }
    __syncthreads();   // all a2 reads done -> safe to overwrite act with msgbuf
    float* msgbuf = (float*)act;   // [56][MRS] f32 (29.6 KB <= 33.8 KB)
    {
        const int c = wv*32 + cl;
        float b3v = msg_b3[c];
        #pragma unroll
        for (int r = 0; r < 16; ++r) {
            int row0 = (r&3) + 8*(r>>2) + 4*g;   // 0..31
            int row1 = 32 + row0;                // 32..63
            msgbuf[row0*MRS + c] = (m0[r] + b3v) * s_gate[row0];
            if (row1 < EEPB)
                msgbuf[row1*MRS + c] = (m1[r] + b3v) * s_gate[row1];
        }
    }
    __syncthreads();

    // ---- aggregate the 7 edges of each node ----
    {
        const int c   = t & 127;
        const int grp = t >> 7;
        #pragma unroll
        for (int p = 0; p < 4; ++p) {
            int nd = grp + p*2;
            float ssum = 0.f;
            #pragma unroll
            for (int q2 = 0; q2 < 7; ++q2) ssum += msgbuf[(nd*7+q2)*MRS + c];
            AGG[(size_t)(base+nd)*128 + c] = ssum;
        }
    }
}

// ---------------- update kernel (MFMA, M=32): u1,u2,u3 + local + final gelu ----------------
#define UM 32

__global__ __launch_bounds__(256, 4)
void update_kernel(const __hip_bfloat16* __restrict__ w1bt, const __hip_bfloat16* __restrict__ w2ut,
                   const __hip_bfloat16* __restrict__ w3ut,
                   const float* __restrict__ upd_b2, const float* __restrict__ upd_b3,
                   const __hip_bfloat16* __restrict__ HU, const float* __restrict__ HL,
                   const float* __restrict__ AGG, const float* __restrict__ TU,
                   float* __restrict__ out)
{
    __shared__ __align__(16) __hip_bfloat16 ub[UM*ARS];   // 16.9 KB, ping-pong in place
    const int t = threadIdx.x;
    const int lane = t & 63, wv = t >> 6;
    const int cl = lane & 31, g = lane >> 5;
    const int base = blockIdx.x * UM;
    const int b = base >> 12;

    #pragma unroll
    for (int i = 0; i < 4; ++i) {          // stage AGG tile (32x128 f32 -> bf16)
        int f = (i*256 + t)*4;
        float4 av = *(const float4*)&AGG[(size_t)base*128 + f];
        int row = f >> 7, col = f & 127;
        s16x4 pk; pk[0]=f2bs(av.x); pk[1]=f2bs(av.y); pk[2]=f2bs(av.z); pk[3]=f2bs(av.w);
        *(s16x4*)&ub[row*ARS + col] = pk;
    }
    __syncthreads();

    // ---- u1 = gelu(HU + TU + agg @ w1b)  K=128, N=256; wave covers cols wv*64..wv*64+63 ----
    f32x16 u0a = zero16(), u1a = zero16();
    {
        const __hip_bfloat16* a0 = ub + (size_t)(cl)*ARS + g*8;
        const __hip_bfloat16* b0 = w1bt + (size_t)(wv*64 + cl)*128 + g*8;
        const __hip_bfloat16* b1 = w1bt + (size_t)(wv*64 + 32 + cl)*128 + g*8;
        #pragma unroll
        for (int kt = 0; kt < 8; ++kt) {
            bf16x8 af = *(const bf16x8*)(a0 + kt*16);
            u0a = MFMA32(af, *(const bf16x8*)(b0 + kt*16), u0a);
            u1a = MFMA32(af, *(const bf16x8*)(b1 + kt*16), u1a);
        }
    }
    __syncthreads();   // staging reads done
    {
        const int c0 = wv*64 + cl, c1 = c0 + 32;
        float tu0 = TU[b*256 + c0], tu1 = TU[b*256 + c1];
        #pragma unroll
        for (int r = 0; r < 16; ++r) {
            int row = (r&3) + 8*(r>>2) + 4*g;
            int n0 = base + row;
            ub[row*ARS + c0] = __float2bfloat16(gelu_f(u0a[r] + tu0 + __bfloat162float(HU[(size_t)n0*256 + c0])));
            ub[row*ARS + c1] = __float2bfloat16(gelu_f(u1a[r] + tu1 + __bfloat162float(HU[(size_t)n0*256 + c1])));
        }
    }
    __syncthreads();

    // ---- u2 = gelu(u1 @ w2u + b2)  K=256, N=256 ----
    f32x16 v0a = zero16(), v1a = zero16();
    {
        const __hip_bfloat16* a0 = ub + (size_t)(cl)*ARS + g*8;
        const __hip_bfloat16* b0 = w2ut + (size_t)(wv*64 + cl)*256 + g*8;
        const __hip_bfloat16* b1 = w2ut + (size_t)(wv*64 + 32 + cl)*256 + g*8;
        #pragma unroll
        for (int kt = 0; kt < 16; ++kt) {
            bf16x8 af = *(const bf16x8*)(a0 + kt*16);
            v0a = MFMA32(af, *(const bf16x8*)(b0 + kt*16), v0a);
            v1a = MFMA32(af, *(const bf16x8*)(b1 + kt*16), v1a);
        }
    }
    __syncthreads();   // u1 reads done
    {
        const int c0 = wv*64 + cl, c1 = c0 + 32;
        float b20 = upd_b2[c0], b21 = upd_b2[c1];
        #pragma unroll
        for (int r = 0; r < 16; ++r) {
            int row = (r&3) + 8*(r>>2) + 4*g;
            ub[row*ARS + c0] = __float2bfloat16(gelu_f(v0a[r] + b20));
            ub[row*ARS + c1] = __float2bfloat16(gelu_f(v1a[r] + b21));
        }
    }
    __syncthreads();

    // ---- out = gelu(u2 @ w3u + b3 + HL)  K=256, N=128; wave covers cols wv*32.. ----
    f32x16 w0a = zero16();
    {
        const __hip_bfloat16* wp = w3ut + (size_t)(wv*32 + cl)*256 + g*8;
        const __hip_bfloat16* a0 = ub + (size_t)(cl)*ARS + g*8;
        #pragma unroll
        for (int kt = 0; kt < 16; ++kt)
            w0a = MFMA32(*(const bf16x8*)(a0 + kt*16), *(const bf16x8*)(wp + kt*16), w0a);
    }
    {
        const int c = wv*32 + cl;
        float b3v = upd_b3[c];
        #pragma unroll
        for (int r = 0; r < 16; ++r) {
            int row = (r&3) + 8*(r>>2) + 4*g;
            size_t o = (size_t)(base+row)*128 + c;
            out[o] = gelu_f(w0a[r] + b3v + HL[o]);
        }
    }
}

// ---------------- launch ----------------
extern "C" void kernel_launch(void* const* d_in, const int* in_sizes, int n_in,
                              void* d_out, int out_size, void* d_ws, size_t ws_size,
                              hipStream_t stream)
{
    const float* h      = (const float*)d_in[0];
    const float* x      = (const float*)d_in[1];
    const float* tau    = (const float*)d_in[2];
    const float* u0     = (const float*)d_in[3];
    const float* msg_w1 = (const float*)d_in[4];
    const float* msg_b1 = (const float*)d_in[5];
    const float* msg_w2 = (const float*)d_in[6];
    const float* msg_b2 = (const float*)d_in[7];
    const float* msg_w3 = (const float*)d_in[8];
    const float* msg_b3 = (const float*)d_in[9];
    const float* gate_w1= (const float*)d_in[10];
    const float* gate_b1= (const float*)d_in[11];
    const float* gate_w2= (const float*)d_in[12];
    const float* gate_b2= (const float*)d_in[13];
    const float* upd_w1 = (const float*)d_in[14];
    const float* upd_b1 = (const float*)d_in[15];
    const float* upd_w2 = (const float*)d_in[16];
    const float* upd_b2 = (const float*)d_in[17];
    const float* upd_w3 = (const float*)d_in[18];
    const float* upd_b3 = (const float*)d_in[19];
    const float* W_w    = (const float*)d_in[20];
    const float* W_b    = (const float*)d_in[21];
    float* out = (float*)d_out;

    char* ws = (char*)d_ws;
    size_t off = 0;
    auto alloc = [&](size_t bytes) -> void* {
        void* p = ws + off;
        off += (bytes + 255) & ~(size_t)255;
        return p;
    };
    __hip_bfloat16* PAm = (__hip_bfloat16*)alloc((size_t)NNODES*256*2);
    __hip_bfloat16* PBm = (__hip_bfloat16*)alloc((size_t)NNODES*256*2);
    __hip_bfloat16* PAg = (__hip_bfloat16*)alloc((size_t)NNODES*256*2);
    __hip_bfloat16* PBg = (__hip_bfloat16*)alloc((size_t)NNODES*256*2);
    __hip_bfloat16* HU  = (__hip_bfloat16*)alloc((size_t)NNODES*256*2);
    float* HL  = (float*)alloc((size_t)NNODES*128*4);
    float* AGG = (float*)alloc((size_t)NNODES*128*4);
    float* TM  = (float*)alloc(8*256*4);
    float* TG  = (float*)alloc(8*256*4);
    float* TU  = (float*)alloc(8*256*4);
    __hip_bfloat16* w2t   = (__hip_bfloat16*)alloc((size_t)256*256*2);
    __hip_bfloat16* w3t   = (__hip_bfloat16*)alloc((size_t)128*256*2);
    __hip_bfloat16* wall_t= (__hip_bfloat16*)alloc((size_t)1408*128*2);
    __hip_bfloat16* w1bt  = (__hip_bfloat16*)alloc((size_t)256*128*2);
    __hip_bfloat16* w2ut  = (__hip_bfloat16*)alloc((size_t)256*256*2);
    __hip_bfloat16* w3ut  = (__hip_bfloat16*)alloc((size_t)128*256*2);
    (void)ws_size; (void)in_sizes; (void)n_in; (void)out_size;

    tau_kernel<<<8, 256, 0, stream>>>(tau, msg_w1, msg_b1, gate_w1, gate_b1,
                                      upd_w1, upd_b1, TM, TG, TU);
    wconv_kernel<<<1600, 256, 0, stream>>>(msg_w2, msg_w3, msg_w1, gate_w1,
                                           upd_w1, upd_w2, upd_w3, W_w,
                                           w2t, w3t, wall_t, w1bt, w2ut, w3ut);
    precompute_kernel<<<dim3(NNODES/64, 11), 256, 0, stream>>>(h, wall_t, W_b,
                                                               PAm, PBm, PAg, PBg, HU, HL);
    edge_kernel<<<NNODES/ENPB, 256, 0, stream>>>(x, u0, msg_w1, gate_w1,
                                                 w2t, msg_b2, w3t, msg_b3,
                                                 gate_w2, gate_b2,
                                                 PAm, PBm, PAg, PBg, TM, TG, AGG);
    update_kernel<<<NNODES/UM, 256, 0, stream>>>(w1bt, w2ut, w3ut, upd_b2, upd_b3,
                                                 HU, HL, AGG, TU, out);
}

// Round 5
// 204.951 us; speedup vs baseline: 16.3549x; 1.1738x over previous
//
#include <hip/hip_runtime.h>
#include <hip/hip_bf16.h>
#include <math.h>

#define NXC 4096
#define NNODES 32768       // B*NX = 8*4096

typedef __attribute__((ext_vector_type(8))) short bf16x8;
typedef __attribute__((ext_vector_type(4))) short s16x4;
typedef __attribute__((ext_vector_type(16))) float f32x16;

#define MFMA32(a,b,c) __builtin_amdgcn_mfma_f32_32x32x16_bf16((a),(b),(c),0,0,0)

// fast tanh-GELU: gelu(v) = v - v/(1+E), E = 2^(c1*v + c2*v^3); max err ~4e-4
__device__ __forceinline__ float gelu_f(float v) {
    float z = v * fmaf(v*v, 0.10294324f, 2.3022082f);
    float e = __builtin_amdgcn_exp2f(z);
    return v - v * __builtin_amdgcn_rcpf(1.0f + e);
}
__device__ __forceinline__ float sigmoid_f(float v) {
    float e = __builtin_amdgcn_exp2f(-1.4426950409f * v);
    return __builtin_amdgcn_rcpf(1.0f + e);
}
__device__ __forceinline__ short f2bs(float x) {
    __hip_bfloat16 b = __float2bfloat16(x);
    union { __hip_bfloat16 h; short s; } u; u.h = b; return u.s;
}
__device__ __forceinline__ f32x16 zero16() {
    f32x16 v;
    #pragma unroll
    for (int i = 0; i < 16; ++i) v[i] = 0.f;
    return v;
}
// DPP quad-perm cross-lane (pure VALU, no LDS pipe)
__device__ __forceinline__ float dpp_xor1(float x) {
    return __int_as_float(__builtin_amdgcn_update_dpp(0, __float_as_int(x), 0xB1, 0xF, 0xF, true));
}
__device__ __forceinline__ float dpp_xor2(float x) {
    return __int_as_float(__builtin_amdgcn_update_dpp(0, __float_as_int(x), 0x4E, 0xF, 0xF, true));
}

// ---------------- tau terms (per batch): TM/TG/TU = tau @ W1_tau + b1 ----------------
__global__ void tau_kernel(const float* __restrict__ tau,
                           const float* __restrict__ msg_w1, const float* __restrict__ msg_b1,
                           const float* __restrict__ gate_w1, const float* __restrict__ gate_b1,
                           const float* __restrict__ upd_w1, const float* __restrict__ upd_b1,
                           float* __restrict__ TM, float* __restrict__ TG, float* __restrict__ TU)
{
    const int b = blockIdx.x;      // 0..7
    const int t = threadIdx.x;     // 0..255
    float tv[16];
    #pragma unroll
    for (int k = 0; k < 16; ++k) tv[k] = tau[b*16 + k];
    float am = msg_b1[t], ag = gate_b1[t], au = upd_b1[t];
    #pragma unroll
    for (int k = 0; k < 16; ++k) {
        am = fmaf(tv[k], msg_w1 [(257+k)*256 + t], am);
        ag = fmaf(tv[k], gate_w1[(257+k)*256 + t], ag);
        au = fmaf(tv[k], upd_w1 [(256+k)*256 + t], au);
    }
    TM[b*256+t] = am; TG[b*256+t] = ag; TU[b*256+t] = au;
}

// ---------------- weight prep: all bf16-transposed weight blocks ----------------
// w2t[256][256], w3t[128][256], wall_t[1024][128] (PAm|PBm|PAg|PBg),
// w1ut[256][256] (upd_w1 rows 0-255), w2ut[256][256], w3ut[128][256], wwt[128][128]
__global__ void wconv_kernel(const float* __restrict__ msg_w2, const float* __restrict__ msg_w3,
                             const float* __restrict__ msg_w1, const float* __restrict__ gate_w1,
                             const float* __restrict__ upd_w1, const float* __restrict__ upd_w2,
                             const float* __restrict__ upd_w3, const float* __restrict__ W_w,
                             __hip_bfloat16* __restrict__ w2t, __hip_bfloat16* __restrict__ w3t,
                             __hip_bfloat16* __restrict__ wall_t, __hip_bfloat16* __restrict__ w1ut,
                             __hip_bfloat16* __restrict__ w2ut, __hip_bfloat16* __restrict__ w3ut,
                             __hip_bfloat16* __restrict__ wwt)
{
    int i = blockIdx.x * 256 + threadIdx.x;   // 0 .. 409599
    if (i < 65536) { int c=i>>8, k=i&255; w2t[i] = __float2bfloat16(msg_w2[k*256+c]); return; }
    i -= 65536;
    if (i < 32768) { int c=i>>8, k=i&255; w3t[i] = __float2bfloat16(msg_w3[k*128+c]); return; }
    i -= 32768;
    if (i < 131072) {
        int c = i>>7, k = i&127; float v;
        if      (c <  256) v = msg_w1 [k*256 + c];
        else if (c <  512) v = msg_w1 [(128+k)*256 + (c-256)];
        else if (c <  768) v = gate_w1[k*256 + (c-512)];
        else               v = gate_w1[(128+k)*256 + (c-768)];
        wall_t[i] = __float2bfloat16(v); return;
    }
    i -= 131072;
    if (i < 65536) { int c=i>>8, k=i&255; w1ut[i] = __float2bfloat16(upd_w1[k*256+c]); return; }
    i -= 65536;
    if (i < 65536) { int c=i>>8, k=i&255; w2ut[i] = __float2bfloat16(upd_w2[k*256+c]); return; }
    i -= 65536;
    if (i < 32768) { int c=i>>8, k=i&255; w3ut[i] = __float2bfloat16(upd_w3[k*128+c]); return; }
    i -= 32768;
    { int c=i>>7, k=i&127; wwt[i] = __float2bfloat16(W_w[k*128+c]); }
}

// ---------------- per-node precompute (MFMA): [PAm|PBm|PAg|PBg] = h @ wall ----------------
#define PSTR 136   // h-tile LDS row stride (bf16), 272 B

__global__ __launch_bounds__(256, 4)
void precompute_kernel(const float* __restrict__ h, const __hip_bfloat16* __restrict__ wall_t,
                       __hip_bfloat16* __restrict__ PAm, __hip_bfloat16* __restrict__ PBm,
                       __hip_bfloat16* __restrict__ PAg, __hip_bfloat16* __restrict__ PBg)
{
    __shared__ __align__(16) __hip_bfloat16 lds[64*256];    // hs view (stride PSTR) then ob view
    const int t = threadIdx.x;
    const int lane = t & 63, wv = t >> 6;
    const int cl = lane & 31, g = lane >> 5;
    const int base = blockIdx.x * 64;
    const int tile = blockIdx.y;   // 0..3

    #pragma unroll
    for (int i = 0; i < 8; ++i) {          // stage h tile (64x128 f32 -> bf16)
        int f = (i*256 + t)*4;
        float4 hv = *(const float4*)&h[(size_t)base*128 + f];
        int row = f >> 7, col = f & 127;
        s16x4 pk; pk[0]=f2bs(hv.x); pk[1]=f2bs(hv.y); pk[2]=f2bs(hv.z); pk[3]=f2bs(hv.w);
        *(s16x4*)&lds[row*PSTR + col] = pk;
    }
    __syncthreads();

    // per wave: cols c0=wv*64+cl, c1=c0+32 of this 256-col tile; rows 0-31 and 32-63
    f32x16 a00 = zero16(), a01 = zero16(), a10 = zero16(), a11 = zero16();
    {
        const int c0 = wv*64 + cl, c1 = c0 + 32;
        const __hip_bfloat16* b0 = wall_t + ((size_t)tile*256 + c0)*128 + g*8;
        const __hip_bfloat16* b1 = wall_t + ((size_t)tile*256 + c1)*128 + g*8;
        const __hip_bfloat16* a0 = lds + (size_t)(cl)*PSTR + g*8;
        const __hip_bfloat16* a1p = lds + (size_t)(32+cl)*PSTR + g*8;
        #pragma unroll
        for (int kt = 0; kt < 8; ++kt) {
            bf16x8 bf0 = *(const bf16x8*)(b0 + kt*16);
            bf16x8 bf1 = *(const bf16x8*)(b1 + kt*16);
            bf16x8 af0 = *(const bf16x8*)(a0 + kt*16);
            bf16x8 af1 = *(const bf16x8*)(a1p + kt*16);
            a00 = MFMA32(af0, bf0, a00);
            a01 = MFMA32(af0, bf1, a01);
            a10 = MFMA32(af1, bf0, a10);
            a11 = MFMA32(af1, bf1, a11);
        }
    }
    __syncthreads();                       // hs reads done; reuse lds as ob[64][256]
    {
        const int c0 = wv*64 + cl, c1 = c0 + 32;
        #pragma unroll
        for (int r = 0; r < 16; ++r) {
            int row = (r&3) + 8*(r>>2) + 4*g;
            lds[row*256 + c0]      = __float2bfloat16(a00[r]);
            lds[row*256 + c1]      = __float2bfloat16(a01[r]);
            lds[(32+row)*256 + c0] = __float2bfloat16(a10[r]);
            lds[(32+row)*256 + c1] = __float2bfloat16(a11[r]);
        }
    }
    __syncthreads();
    {
        __hip_bfloat16* bufs[4] = {PAm, PBm, PAg, PBg};
        __hip_bfloat16* dst = bufs[tile];
        #pragma unroll
        for (int i = 0; i < 8; ++i) {
            int idx = i*256 + t;               // 64 rows x 32 chunks of 8 bf16
            int row = idx >> 5, ch = idx & 31;
            *(float4*)&dst[(size_t)(base+row)*256 + ch*8] =
                *(const float4*)&lds[row*256 + ch*8];
        }
    }
}

// ---------------- fused edge kernel: layer1(VALU) -> MFMA layer2 -> MFMA layer3 -> agg ----------------
#define ENPB 8     // nodes per block
#define EEPB 56    // edges per block
#define ARS  264   // activation row stride in bf16 (528 B, odd multiple of 16 B)
#define MRS  132   // msgbuf row stride in f32 (528 B)

__global__ __launch_bounds__(256, 4)
void edge_kernel(const float* __restrict__ x, const float* __restrict__ u0,
                 const float* __restrict__ msg_w1, const float* __restrict__ gate_w1,
                 const __hip_bfloat16* __restrict__ w2t, const float* __restrict__ msg_b2,
                 const __hip_bfloat16* __restrict__ w3t, const float* __restrict__ msg_b3,
                 const float* __restrict__ gate_w2, const float* __restrict__ gate_b2,
                 const __hip_bfloat16* __restrict__ PAm, const __hip_bfloat16* __restrict__ PBm,
                 const __hip_bfloat16* __restrict__ PAg, const __hip_bfloat16* __restrict__ PBg,
                 const float* __restrict__ TM, const float* __restrict__ TG,
                 float* __restrict__ AGG)
{
    __shared__ __align__(16) __hip_bfloat16 act[64*ARS];   // a1 -> a2 -> msgbuf(f32)
    __shared__ float s_gp[4][EEPB];
    __shared__ float s_rel[EEPB], s_du[EEPB], s_ad[EEPB];
    __shared__ int   s_slotj[14];
    __shared__ float s_gate[EEPB];

    const int t    = threadIdx.x;
    const int lane = t & 63;
    const int wv   = t >> 6;
    const int base = blockIdx.x * ENPB;
    const int b    = base >> 12;
    const int ii0  = base & (NXC-1);

    if (t < 14) {
        int jj = ii0 - 3 + t;
        jj = jj < 0 ? 0 : (jj > NXC-1 ? NXC-1 : jj);
        s_slotj[t] = b*NXC + jj;
    }
    if (t < EEPB) {
        int nd = t / 7, s = t - nd*7;
        int i  = base + nd;
        int jj = ii0 + nd + s - 3;
        jj = jj < 0 ? 0 : (jj > NXC-1 ? NXC-1 : jj);
        int j = b*NXC + jj;
        float rel = x[j] - x[i];
        float du  = u0[i] - u0[j];
        s_rel[t] = rel; s_du[t] = du; s_ad[t] = fabsf(du);
    }
    __syncthreads();

    // ---- phase 1: decomposed layer-1; msg gelu -> act; gate via quad-DPP transpose-reduce ----
    {
        float wr  = msg_w1 [256*256+t], wd  = msg_w1 [273*256+t], wa  = msg_w1 [274*256+t];
        float gwr = gate_w1[256*256+t], gwd = gate_w1[273*256+t], gwa = gate_w1[274*256+t];
        float tm = TM[b*256+t], tg = TG[b*256+t];
        float g2 = gate_w2[t];
        float bm[14], bg[14], pam[8], pag[8], sacc[14];
        #pragma unroll
        for (int q = 0; q < 14; ++q) {
            size_t o = (size_t)s_slotj[q]*256 + t;
            bm[q] = __bfloat162float(PBm[o]) + tm;
            bg[q] = __bfloat162float(PBg[o]) + tg;
        }
        #pragma unroll
        for (int nd = 0; nd < 8; ++nd) {
            size_t o = (size_t)(base+nd)*256 + t;
            pam[nd] = __bfloat162float(PAm[o]);
            pag[nd] = __bfloat162float(PAg[o]);
        }
        const bool p1 = (lane & 1), p2 = ((lane & 2) != 0);
        #pragma unroll
        for (int m = 0; m < 14; ++m) {
            float gq[4];
            #pragma unroll
            for (int r4i = 0; r4i < 4; ++r4i) {
                const int e = m*4 + r4i;
                const int nd = e / 7, s = e - nd*7, q = nd + s;
                float rel = s_rel[e], du = s_du[e], ad = s_ad[e];
                float pm = pam[nd] + bm[q];
                pm = fmaf(rel, wr, pm); pm = fmaf(du, wd, pm); pm = fmaf(ad, wa, pm);
                act[e*ARS + t] = __float2bfloat16(gelu_f(pm));
                float pg = pag[nd] + bg[q];
                pg = fmaf(rel, gwr, pg); pg = fmaf(du, gwd, pg); pg = fmaf(ad, gwa, pg);
                gq[r4i] = gelu_f(pg) * g2;
            }
            // 4x4 quad transpose-reduce: lane%4==r ends up with quad-sum of gq[r]
            float xx = p1 ? gq[1] : gq[0], yy = p1 ? gq[0] : gq[1];
            xx += dpp_xor1(yy);
            float zz = p1 ? gq[3] : gq[2], ww = p1 ? gq[2] : gq[3];
            zz += dpp_xor1(ww);
            float uu = p2 ? zz : xx, vv = p2 ? xx : zz;
            uu += dpp_xor2(vv);
            sacc[m] = uu;
        }
        #pragma unroll
        for (int m = 0; m < 14; ++m) {
            float v = sacc[m];
            v += __shfl_xor(v, 4);
            v += __shfl_xor(v, 8);
            v += __shfl_xor(v, 16);
            v += __shfl_xor(v, 32);
            if (lane < 4) s_gp[wv][m*4 + lane] = v;
        }
    }
    __syncthreads();
    if (t < EEPB)
        s_gate[t] = sigmoid_f(s_gp[0][t] + s_gp[1][t] + s_gp[2][t] + s_gp[3][t] + gate_b2[0]);
    // (s_gate consumed after later barriers)

    // ---- layer 2: a2 = gelu(a1 @ w2 + b2)  [MFMA 32x32x16 bf16] ----
    const int cl = lane & 31;
    const int g  = lane >> 5;
    f32x16 acc00 = zero16(), acc01 = zero16(), acc10 = zero16(), acc11 = zero16();
    {
        const __hip_bfloat16* w2a = w2t + (size_t)((wv*2+0)*32 + cl)*256 + g*8;
        const __hip_bfloat16* w2b = w2t + (size_t)((wv*2+1)*32 + cl)*256 + g*8;
        const __hip_bfloat16* a1a = act + (size_t)(cl)*ARS + g*8;
        const __hip_bfloat16* a1b = act + (size_t)(32+cl)*ARS + g*8;
        #pragma unroll
        for (int kt = 0; kt < 16; ++kt) {
            bf16x8 bfa = *(const bf16x8*)(w2a + kt*16);
            bf16x8 bfb = *(const bf16x8*)(w2b + kt*16);
            bf16x8 afa = *(const bf16x8*)(a1a + kt*16);
            bf16x8 afb = *(const bf16x8*)(a1b + kt*16);
            acc00 = MFMA32(afa, bfa, acc00);
            acc01 = MFMA32(afa, bfb, acc01);
            acc10 = MFMA32(afb, bfa, acc10);
            acc11 = MFMA32(afb, bfb, acc11);
        }
    }
    __syncthreads();   // all a1 reads done -> safe to overwrite act with a2
    {
        const int c0 = (wv*2+0)*32 + cl;
        const int c1 = (wv*2+1)*32 + cl;
        float b20 = msg_b2[c0], b21 = msg_b2[c1];
        #pragma unroll
        for (int r = 0; r < 16; ++r) {
            int row0 = (r&3) + 8*(r>>2) + 4*g;
            act[row0*ARS + c0] = __float2bfloat16(gelu_f(acc00[r] + b20));
            act[row0*ARS + c1] = __float2bfloat16(gelu_f(acc01[r] + b21));
            if (r < 12) {  // rows 32+row0 >= 56 are pad: skip
                int row1 = 32 + row0;
                act[row1*ARS + c0] = __float2bfloat16(gelu_f(acc10[r] + b20));
                act[row1*ARS + c1] = __float2bfloat16(gelu_f(acc11[r] + b21));
            }
        }
    }
    __syncthreads();   // a2 complete

    // ---- layer 3: msg = (a2 @ w3 + b3) * gate  [MFMA 32x32x16 bf16] ----
    f32x16 m0 = zero16(), m1 = zero16();
    {
        const __hip_bfloat16* w3p = w3t + (size_t)(wv*32 + cl)*256 + g*8;
        const __hip_bfloat16* a2a = act + (size_t)(cl)*ARS + g*8;
        const __hip_bfloat16* a2b = act + (size_t)(32+cl)*ARS + g*8;
        #pragma unroll
        for (int kt = 0; kt < 16; ++kt) {
            bf16x8 bfr = *(const bf16x8*)(w3p + kt*16);
            m0 = MFMA32(*(const bf16x8*)(a2a + kt*16), bfr, m0);
            m1 = MFMA32(*(const bf16x8*)(a2b + kt*16), bfr, m1);
        }
    }
    __syncthreads();   // all a2 reads done -> safe to overwrite act with msgbuf
    float* msgbuf = (float*)act;   // [56][MRS] f32
    {
        const int c = wv*32 + cl;
        float b3v = msg_b3[c];
        #pragma unroll
        for (int r = 0; r < 16; ++r) {
            int row0 = (r&3) + 8*(r>>2) + 4*g;   // 0..31
            int row1 = 32 + row0;                // 32..63
            msgbuf[row0*MRS + c] = (m0[r] + b3v) * s_gate[row0];
            if (row1 < EEPB)
                msgbuf[row1*MRS + c] = (m1[r] + b3v) * s_gate[row1];
        }
    }
    __syncthreads();

    // ---- aggregate the 7 edges of each node ----
    {
        const int c   = t & 127;
        const int grp = t >> 7;
        #pragma unroll
        for (int p = 0; p < 4; ++p) {
            int nd = grp + p*2;
            float ssum = 0.f;
            #pragma unroll
            for (int q2 = 0; q2 < 7; ++q2) ssum += msgbuf[(nd*7+q2)*MRS + c];
            AGG[(size_t)(base+nd)*128 + c] = ssum;
        }
    }
}

// ---------------- update kernel (MFMA, M=32): u1 (incl h-part), u2, u3 + local + final gelu ----------------
#define UM 32

__global__ __launch_bounds__(256, 4)
void update_kernel(const __hip_bfloat16* __restrict__ w1ut, const __hip_bfloat16* __restrict__ w2ut,
                   const __hip_bfloat16* __restrict__ w3ut, const __hip_bfloat16* __restrict__ wwt,
                   const float* __restrict__ upd_b2, const float* __restrict__ upd_b3,
                   const float* __restrict__ W_b,
                   const float* __restrict__ h, const float* __restrict__ AGG,
                   const float* __restrict__ TU,
                   float* __restrict__ out)
{
    __shared__ __align__(16) __hip_bfloat16 ub[UM*ARS];   // [h|agg] -> u1 -> u2, in place
    const int t = threadIdx.x;
    const int lane = t & 63, wv = t >> 6;
    const int cl = lane & 31, g = lane >> 5;
    const int base = blockIdx.x * UM;
    const int b = base >> 12;

    #pragma unroll
    for (int i = 0; i < 4; ++i) {          // stage [h | AGG] tile (32 x 256 bf16)
        int f = (i*256 + t)*4;
        int row = f >> 7, col = f & 127;
        float4 hv = *(const float4*)&h[(size_t)base*128 + f];
        s16x4 pk; pk[0]=f2bs(hv.x); pk[1]=f2bs(hv.y); pk[2]=f2bs(hv.z); pk[3]=f2bs(hv.w);
        *(s16x4*)&ub[row*ARS + col] = pk;
        float4 av = *(const float4*)&AGG[(size_t)base*128 + f];
        s16x4 pa; pa[0]=f2bs(av.x); pa[1]=f2bs(av.y); pa[2]=f2bs(av.z); pa[3]=f2bs(av.w);
        *(s16x4*)&ub[row*ARS + 128 + col] = pa;
    }
    __syncthreads();

    // ---- u1 = gelu([h|agg] @ upd_w1[0:256] + TU)  K=256, N=256 ----
    // ---- also HL = h @ W_w (K=128, N=128), kept in registers ----
    f32x16 u0a = zero16(), u1a = zero16(), hl = zero16();
    {
        const __hip_bfloat16* a0 = ub + (size_t)(cl)*ARS + g*8;
        const __hip_bfloat16* b0 = w1ut + (size_t)(wv*64 + cl)*256 + g*8;
        const __hip_bfloat16* b1 = w1ut + (size_t)(wv*64 + 32 + cl)*256 + g*8;
        const __hip_bfloat16* bw = wwt + (size_t)(wv*32 + cl)*128 + g*8;
        #pragma unroll
        for (int kt = 0; kt < 16; ++kt) {
            bf16x8 af = *(const bf16x8*)(a0 + kt*16);
            u0a = MFMA32(af, *(const bf16x8*)(b0 + kt*16), u0a);
            u1a = MFMA32(af, *(const bf16x8*)(b1 + kt*16), u1a);
            if (kt < 8)
                hl = MFMA32(af, *(const bf16x8*)(bw + kt*16), hl);
        }
    }
    __syncthreads();   // staging reads done
    {
        const int c0 = wv*64 + cl, c1 = c0 + 32;
        float tu0 = TU[b*256 + c0], tu1 = TU[b*256 + c1];
        #pragma unroll
        for (int r = 0; r < 16; ++r) {
            int row = (r&3) + 8*(r>>2) + 4*g;
            ub[row*ARS + c0] = __float2bfloat16(gelu_f(u0a[r] + tu0));
            ub[row*ARS + c1] = __float2bfloat16(gelu_f(u1a[r] + tu1));
        }
    }
    __syncthreads();

    // ---- u2 = gelu(u1 @ w2u + b2)  K=256, N=256 ----
    f32x16 v0a = zero16(), v1a = zero16();
    {
        const __hip_bfloat16* a0 = ub + (size_t)(cl)*ARS + g*8;
        const __hip_bfloat16* b0 = w2ut + (size_t)(wv*64 + cl)*256 + g*8;
        const __hip_bfloat16* b1 = w2ut + (size_t)(wv*64 + 32 + cl)*256 + g*8;
        #pragma unroll
        for (int kt = 0; kt < 16; ++kt) {
            bf16x8 af = *(const bf16x8*)(a0 + kt*16);
            v0a = MFMA32(af, *(const bf16x8*)(b0 + kt*16), v0a);
            v1a = MFMA32(af, *(const bf16x8*)(b1 + kt*16), v1a);
        }
    }
    __syncthreads();   // u1 reads done
    {
        const int c0 = wv*64 + cl, c1 = c0 + 32;
        float b20 = upd_b2[c0], b21 = upd_b2[c1];
        #pragma unroll
        for (int r = 0; r < 16; ++r) {
            int row = (r&3) + 8*(r>>2) + 4*g;
            ub[row*ARS + c0] = __float2bfloat16(gelu_f(v0a[r] + b20));
            ub[row*ARS + c1] = __float2bfloat16(gelu_f(v1a[r] + b21));
        }
    }
    __syncthreads();

    // ---- out = gelu(u2 @ w3u + b3 + HL + W_b)  K=256, N=128 ----
    f32x16 w0a = zero16();
    {
        const __hip_bfloat16* wp = w3ut + (size_t)(wv*32 + cl)*256 + g*8;
        const __hip_bfloat16* a0 = ub + (size_t)(cl)*ARS + g*8;
        #pragma unroll
        for (int kt = 0; kt < 16; ++kt)
            w0a = MFMA32(*(const bf16x8*)(a0 + kt*16), *(const bf16x8*)(wp + kt*16), w0a);
    }
    {
        const int c = wv*32 + cl;
        float b3v = upd_b3[c] + W_b[c];
        #pragma unroll
        for (int r = 0; r < 16; ++r) {
            int row = (r&3) + 8*(r>>2) + 4*g;
            size_t o = (size_t)(base+row)*128 + c;
            out[o] = gelu_f(w0a[r] + b3v + hl[r]);
        }
    }
}

// ---------------- launch ----------------
extern "C" void kernel_launch(void* const* d_in, const int* in_sizes, int n_in,
                              void* d_out, int out_size, void* d_ws, size_t ws_size,
                              hipStream_t stream)
{
    const float* h      = (const float*)d_in[0];
    const float* x      = (const float*)d_in[1];
    const float* tau    = (const float*)d_in[2];
    const float* u0     = (const float*)d_in[3];
    const float* msg_w1 = (const float*)d_in[4];
    const float* msg_b1 = (const float*)d_in[5];
    const float* msg_w2 = (const float*)d_in[6];
    const float* msg_b2 = (const float*)d_in[7];
    const float* msg_w3 = (const float*)d_in[8];
    const float* msg_b3 = (const float*)d_in[9];
    const float* gate_w1= (const float*)d_in[10];
    const float* gate_b1= (const float*)d_in[11];
    const float* gate_w2= (const float*)d_in[12];
    const float* gate_b2= (const float*)d_in[13];
    const float* upd_w1 = (const float*)d_in[14];
    const float* upd_b1 = (const float*)d_in[15];
    const float* upd_w2 = (const float*)d_in[16];
    const float* upd_b2 = (const float*)d_in[17];
    const float* upd_w3 = (const float*)d_in[18];
    const float* upd_b3 = (const float*)d_in[19];
    const float* W_w    = (const float*)d_in[20];
    const float* W_b    = (const float*)d_in[21];
    float* out = (float*)d_out;

    char* ws = (char*)d_ws;
    size_t off = 0;
    auto alloc = [&](size_t bytes) -> void* {
        void* p = ws + off;
        off += (bytes + 255) & ~(size_t)255;
        return p;
    };
    __hip_bfloat16* PAm = (__hip_bfloat16*)alloc((size_t)NNODES*256*2);
    __hip_bfloat16* PBm = (__hip_bfloat16*)alloc((size_t)NNODES*256*2);
    __hip_bfloat16* PAg = (__hip_bfloat16*)alloc((size_t)NNODES*256*2);
    __hip_bfloat16* PBg = (__hip_bfloat16*)alloc((size_t)NNODES*256*2);
    float* AGG = (float*)alloc((size_t)NNODES*128*4);
    float* TM  = (float*)alloc(8*256*4);
    float* TG  = (float*)alloc(8*256*4);
    float* TU  = (float*)alloc(8*256*4);
    __hip_bfloat16* w2t   = (__hip_bfloat16*)alloc((size_t)256*256*2);
    __hip_bfloat16* w3t   = (__hip_bfloat16*)alloc((size_t)128*256*2);
    __hip_bfloat16* wall_t= (__hip_bfloat16*)alloc((size_t)1024*128*2);
    __hip_bfloat16* w1ut  = (__hip_bfloat16*)alloc((size_t)256*256*2);
    __hip_bfloat16* w2ut  = (__hip_bfloat16*)alloc((size_t)256*256*2);
    __hip_bfloat16* w3ut  = (__hip_bfloat16*)alloc((size_t)128*256*2);
    __hip_bfloat16* wwt   = (__hip_bfloat16*)alloc((size_t)128*128*2);
    (void)ws_size; (void)in_sizes; (void)n_in; (void)out_size;

    tau_kernel<<<8, 256, 0, stream>>>(tau, msg_w1, msg_b1, gate_w1, gate_b1,
                                      upd_w1, upd_b1, TM, TG, TU);
    wconv_kernel<<<1600, 256, 0, stream>>>(msg_w2, msg_w3, msg_w1, gate_w1,
                                           upd_w1, upd_w2, upd_w3, W_w,
                                           w2t, w3t, wall_t, w1ut, w2ut, w3ut, wwt);
    precompute_kernel<<<dim3(NNODES/64, 4), 256, 0, stream>>>(h, wall_t,
                                                              PAm, PBm, PAg, PBg);
    edge_kernel<<<NNODES/ENPB, 256, 0, stream>>>(x, u0, msg_w1, gate_w1,
                                                 w2t, msg_b2, w3t, msg_b3,
                                                 gate_w2, gate_b2,
                                                 PAm, PBm, PAg, PBg, TM, TG, AGG);
    update_kernel<<<NNODES/UM, 256, 0, stream>>>(w1ut, w2ut, w3ut, wwt,
                                                 upd_b2, upd_b3, W_b,
                                                 h, AGG, TU, out);
}

// Round 6
// 200.434 us; speedup vs baseline: 16.7235x; 1.0225x over previous
//
#include <hip/hip_runtime.h>
#include <hip/hip_bf16.h>
#include <math.h>

#define NXC 4096
#define NNODES 32768       // B*NX = 8*4096

typedef __attribute__((ext_vector_type(8))) short bf16x8;
typedef __attribute__((ext_vector_type(4))) short s16x4;
typedef __attribute__((ext_vector_type(16))) float f32x16;
typedef __attribute__((ext_vector_type(2))) float f32x2;

#define MFMA32(a,b,c) __builtin_amdgcn_mfma_f32_32x32x16_bf16((a),(b),(c),0,0,0)

// fast tanh-GELU: gelu(v) = v - v/(1+E), E = 2^(c1*v + c2*v^3); max err ~4e-4
__device__ __forceinline__ float gelu_f(float v) {
    float z = v * fmaf(v*v, 0.10294324f, 2.3022082f);
    float e = __builtin_amdgcn_exp2f(z);
    return v - v * __builtin_amdgcn_rcpf(1.0f + e);
}
// packed-pair GELU: non-trans ops become v_pk_* on gfx950
__device__ __forceinline__ f32x2 gelu2(f32x2 v) {
    const f32x2 c1 = {0.10294324f, 0.10294324f};
    const f32x2 c2 = {2.3022082f, 2.3022082f};
    f32x2 z = v * __builtin_elementwise_fma(v*v, c1, c2);
    f32x2 r;
    r[0] = __builtin_amdgcn_rcpf(1.0f + __builtin_amdgcn_exp2f(z[0]));
    r[1] = __builtin_amdgcn_rcpf(1.0f + __builtin_amdgcn_exp2f(z[1]));
    return v - v * r;
}
__device__ __forceinline__ float sigmoid_f(float v) {
    float e = __builtin_amdgcn_exp2f(-1.4426950409f * v);
    return __builtin_amdgcn_rcpf(1.0f + e);
}
__device__ __forceinline__ short f2bs(float x) {
    __hip_bfloat16 b = __float2bfloat16(x);
    union { __hip_bfloat16 h; short s; } u; u.h = b; return u.s;
}
__device__ __forceinline__ f32x16 zero16() {
    f32x16 v;
    #pragma unroll
    for (int i = 0; i < 16; ++i) v[i] = 0.f;
    return v;
}
// DPP quad-perm cross-lane (pure VALU, no LDS pipe)
__device__ __forceinline__ float dpp_xor1(float x) {
    return __int_as_float(__builtin_amdgcn_update_dpp(0, __float_as_int(x), 0xB1, 0xF, 0xF, true));
}
__device__ __forceinline__ float dpp_xor2(float x) {
    return __int_as_float(__builtin_amdgcn_update_dpp(0, __float_as_int(x), 0x4E, 0xF, 0xF, true));
}

// ---------------- weight prep + tau terms (fused) ----------------
// w2t[256][256], w3t[128][256], wall_t[1024][128] (PAm|PBm|PAg|PBg),
// w1ut[256][256], w2ut[256][256], w3ut[128][256], wwt[128][128]; blocks >=1600: tau
__global__ void wconv_kernel(const float* __restrict__ msg_w2, const float* __restrict__ msg_w3,
                             const float* __restrict__ msg_w1, const float* __restrict__ gate_w1,
                             const float* __restrict__ upd_w1, const float* __restrict__ upd_w2,
                             const float* __restrict__ upd_w3, const float* __restrict__ W_w,
                             const float* __restrict__ tau,
                             const float* __restrict__ msg_b1, const float* __restrict__ gate_b1,
                             const float* __restrict__ upd_b1,
                             __hip_bfloat16* __restrict__ w2t, __hip_bfloat16* __restrict__ w3t,
                             __hip_bfloat16* __restrict__ wall_t, __hip_bfloat16* __restrict__ w1ut,
                             __hip_bfloat16* __restrict__ w2ut, __hip_bfloat16* __restrict__ w3ut,
                             __hip_bfloat16* __restrict__ wwt,
                             float* __restrict__ TM, float* __restrict__ TG, float* __restrict__ TU)
{
    if (blockIdx.x >= 1600) {   // tau terms for batch b
        const int b = blockIdx.x - 1600;   // 0..7
        const int t = threadIdx.x;
        float tv[16];
        #pragma unroll
        for (int k = 0; k < 16; ++k) tv[k] = tau[b*16 + k];
        float am = msg_b1[t], ag = gate_b1[t], au = upd_b1[t];
        #pragma unroll
        for (int k = 0; k < 16; ++k) {
            am = fmaf(tv[k], msg_w1 [(257+k)*256 + t], am);
            ag = fmaf(tv[k], gate_w1[(257+k)*256 + t], ag);
            au = fmaf(tv[k], upd_w1 [(256+k)*256 + t], au);
        }
        TM[b*256+t] = am; TG[b*256+t] = ag; TU[b*256+t] = au;
        return;
    }
    int i = blockIdx.x * 256 + threadIdx.x;   // 0 .. 409599
    if (i < 65536) { int c=i>>8, k=i&255; w2t[i] = __float2bfloat16(msg_w2[k*256+c]); return; }
    i -= 65536;
    if (i < 32768) { int c=i>>8, k=i&255; w3t[i] = __float2bfloat16(msg_w3[k*128+c]); return; }
    i -= 32768;
    if (i < 131072) {
        int c = i>>7, k = i&127; float v;
        if      (c <  256) v = msg_w1 [k*256 + c];
        else if (c <  512) v = msg_w1 [(128+k)*256 + (c-256)];
        else if (c <  768) v = gate_w1[k*256 + (c-512)];
        else               v = gate_w1[(128+k)*256 + (c-768)];
        wall_t[i] = __float2bfloat16(v); return;
    }
    i -= 131072;
    if (i < 65536) { int c=i>>8, k=i&255; w1ut[i] = __float2bfloat16(upd_w1[k*256+c]); return; }
    i -= 65536;
    if (i < 65536) { int c=i>>8, k=i&255; w2ut[i] = __float2bfloat16(upd_w2[k*256+c]); return; }
    i -= 65536;
    if (i < 32768) { int c=i>>8, k=i&255; w3ut[i] = __float2bfloat16(upd_w3[k*128+c]); return; }
    i -= 32768;
    { int c=i>>7, k=i&127; wwt[i] = __float2bfloat16(W_w[k*128+c]); }
}

// ---------------- per-node precompute (MFMA): [PAm|PBm|PAg|PBg] = h @ wall ----------------
#define PSTR 136   // h-tile LDS row stride (bf16), 272 B

__global__ __launch_bounds__(256, 3)
void precompute_kernel(const float* __restrict__ h, const __hip_bfloat16* __restrict__ wall_t,
                       __hip_bfloat16* __restrict__ PAm, __hip_bfloat16* __restrict__ PBm,
                       __hip_bfloat16* __restrict__ PAg, __hip_bfloat16* __restrict__ PBg)
{
    __shared__ __align__(16) __hip_bfloat16 hs[64*PSTR];   // 17.4 KB, staged once
    __shared__ __align__(16) __hip_bfloat16 ob[64*256];    // 32.8 KB, per-tile C staging
    const int t = threadIdx.x;
    const int lane = t & 63, wv = t >> 6;
    const int cl = lane & 31, g = lane >> 5;
    const int base = blockIdx.x * 64;

    #pragma unroll
    for (int i = 0; i < 8; ++i) {          // stage h tile (64x128 f32 -> bf16)
        int f = (i*256 + t)*4;
        float4 hv = *(const float4*)&h[(size_t)base*128 + f];
        int row = f >> 7, col = f & 127;
        s16x4 pk; pk[0]=f2bs(hv.x); pk[1]=f2bs(hv.y); pk[2]=f2bs(hv.z); pk[3]=f2bs(hv.w);
        *(s16x4*)&hs[row*PSTR + col] = pk;
    }
    __syncthreads();

    __hip_bfloat16* bufs[4] = {PAm, PBm, PAg, PBg};
    const int c0 = wv*64 + cl, c1 = c0 + 32;
    const __hip_bfloat16* a0  = hs + (size_t)(cl)*PSTR + g*8;
    const __hip_bfloat16* a1p = hs + (size_t)(32+cl)*PSTR + g*8;

    for (int tile = 0; tile < 4; ++tile) {
        f32x16 a00 = zero16(), a01 = zero16(), a10 = zero16(), a11 = zero16();
        {
            const __hip_bfloat16* b0 = wall_t + ((size_t)tile*256 + c0)*128 + g*8;
            const __hip_bfloat16* b1 = wall_t + ((size_t)tile*256 + c1)*128 + g*8;
            #pragma unroll
            for (int kt = 0; kt < 8; ++kt) {
                bf16x8 bf0 = *(const bf16x8*)(b0 + kt*16);
                bf16x8 bf1 = *(const bf16x8*)(b1 + kt*16);
                bf16x8 af0 = *(const bf16x8*)(a0 + kt*16);
                bf16x8 af1 = *(const bf16x8*)(a1p + kt*16);
                a00 = MFMA32(af0, bf0, a00);
                a01 = MFMA32(af0, bf1, a01);
                a10 = MFMA32(af1, bf0, a10);
                a11 = MFMA32(af1, bf1, a11);
            }
        }
        #pragma unroll
        for (int r = 0; r < 16; ++r) {
            int row = (r&3) + 8*(r>>2) + 4*g;
            ob[row*256 + c0]      = __float2bfloat16(a00[r]);
            ob[row*256 + c1]      = __float2bfloat16(a01[r]);
            ob[(32+row)*256 + c0] = __float2bfloat16(a10[r]);
            ob[(32+row)*256 + c1] = __float2bfloat16(a11[r]);
        }
        __syncthreads();
        __hip_bfloat16* dst = bufs[tile];
        #pragma unroll
        for (int i = 0; i < 8; ++i) {
            int idx = i*256 + t;               // 64 rows x 32 chunks of 8 bf16
            int row = idx >> 5, ch = idx & 31;
            *(float4*)&dst[(size_t)(base+row)*256 + ch*8] =
                *(const float4*)&ob[row*256 + ch*8];
        }
        __syncthreads();                       // ob reads done before next tile writes
    }
}

// ---------------- fused edge kernel: layer1(VALU, packed) -> MFMA layer2 -> MFMA layer3 -> agg ----------------
#define ENPB 8     // nodes per block
#define EEPB 56    // edges per block
#define ARS  264   // activation row stride in bf16 (528 B, odd multiple of 16 B)
#define MRS  132   // msgbuf row stride in f32 (528 B)

__global__ __launch_bounds__(256, 4)
void edge_kernel(const float* __restrict__ x, const float* __restrict__ u0,
                 const float* __restrict__ msg_w1, const float* __restrict__ gate_w1,
                 const __hip_bfloat16* __restrict__ w2t, const float* __restrict__ msg_b2,
                 const __hip_bfloat16* __restrict__ w3t, const float* __restrict__ msg_b3,
                 const float* __restrict__ gate_w2, const float* __restrict__ gate_b2,
                 const __hip_bfloat16* __restrict__ PAm, const __hip_bfloat16* __restrict__ PBm,
                 const __hip_bfloat16* __restrict__ PAg, const __hip_bfloat16* __restrict__ PBg,
                 const float* __restrict__ TM, const float* __restrict__ TG,
                 __hip_bfloat16* __restrict__ AGG)
{
    __shared__ __align__(16) __hip_bfloat16 act[64*ARS];   // a1 -> a2 -> msgbuf(f32)
    __shared__ __align__(16) float s_rel[EEPB], s_du[EEPB], s_ad[EEPB];
    __shared__ float s_gp[4][EEPB];
    __shared__ int   s_slotj[14];
    __shared__ float s_gate[EEPB];

    const int t    = threadIdx.x;
    const int lane = t & 63;
    const int wv   = t >> 6;
    const int base = blockIdx.x * ENPB;
    const int b    = base >> 12;
    const int ii0  = base & (NXC-1);

    if (t < 14) {
        int jj = ii0 - 3 + t;
        jj = jj < 0 ? 0 : (jj > NXC-1 ? NXC-1 : jj);
        s_slotj[t] = b*NXC + jj;
    }
    if (t < EEPB) {
        int nd = t / 7, s = t - nd*7;
        int i  = base + nd;
        int jj = ii0 + nd + s - 3;
        jj = jj < 0 ? 0 : (jj > NXC-1 ? NXC-1 : jj);
        int j = b*NXC + jj;
        float rel = x[j] - x[i];
        float du  = u0[i] - u0[j];
        s_rel[t] = rel; s_du[t] = du; s_ad[t] = fabsf(du);
    }
    __syncthreads();

    // ---- phase 1: decomposed layer-1, packed edge pairs; gate via quad-DPP reduce ----
    {
        float wr  = msg_w1 [256*256+t], wd  = msg_w1 [273*256+t], wa  = msg_w1 [274*256+t];
        float gwr = gate_w1[256*256+t], gwd = gate_w1[273*256+t], gwa = gate_w1[274*256+t];
        float tm = TM[b*256+t], tg = TG[b*256+t];
        float g2 = gate_w2[t];
        const f32x2 wr2  = {wr, wr},  wd2  = {wd, wd},  wa2  = {wa, wa};
        const f32x2 gwr2 = {gwr,gwr}, gwd2 = {gwd,gwd}, gwa2 = {gwa,gwa};
        const f32x2 g22  = {g2, g2};
        float bm[14], bg[14], pam[8], pag[8], sacc[14];
        #pragma unroll
        for (int q = 0; q < 14; ++q) {
            size_t o = (size_t)s_slotj[q]*256 + t;
            bm[q] = __bfloat162float(PBm[o]) + tm;
            bg[q] = __bfloat162float(PBg[o]) + tg;
        }
        #pragma unroll
        for (int nd = 0; nd < 8; ++nd) {
            size_t o = (size_t)(base+nd)*256 + t;
            pam[nd] = __bfloat162float(PAm[o]);
            pag[nd] = __bfloat162float(PAg[o]);
        }
        const bool p1 = (lane & 1), p2 = ((lane & 2) != 0);
        #pragma unroll
        for (int mq = 0; mq < 14; ++mq) {
            float gq[4];
            #pragma unroll
            for (int pp = 0; pp < 2; ++pp) {
                const int e0 = mq*4 + pp*2, e1 = e0 + 1;
                const int nd0 = e0/7, q0 = nd0 + (e0 - nd0*7);
                const int nd1 = e1/7, q1 = nd1 + (e1 - nd1*7);
                f32x2 rel = *(const f32x2*)&s_rel[e0];
                f32x2 du  = *(const f32x2*)&s_du[e0];
                f32x2 ad  = *(const f32x2*)&s_ad[e0];
                f32x2 pm; pm[0] = pam[nd0] + bm[q0]; pm[1] = pam[nd1] + bm[q1];
                pm = __builtin_elementwise_fma(rel, wr2, pm);
                pm = __builtin_elementwise_fma(du,  wd2, pm);
                pm = __builtin_elementwise_fma(ad,  wa2, pm);
                f32x2 gm = gelu2(pm);
                act[e0*ARS + t] = __float2bfloat16(gm[0]);
                act[e1*ARS + t] = __float2bfloat16(gm[1]);
                f32x2 pg; pg[0] = pag[nd0] + bg[q0]; pg[1] = pag[nd1] + bg[q1];
                pg = __builtin_elementwise_fma(rel, gwr2, pg);
                pg = __builtin_elementwise_fma(du,  gwd2, pg);
                pg = __builtin_elementwise_fma(ad,  gwa2, pg);
                f32x2 gg = gelu2(pg) * g22;
                gq[pp*2] = gg[0]; gq[pp*2+1] = gg[1];
            }
            // 4x4 quad transpose-reduce: lane%4==r ends up with quad-sum of gq[r]
            float xx = p1 ? gq[1] : gq[0], yy = p1 ? gq[0] : gq[1];
            xx += dpp_xor1(yy);
            float zz = p1 ? gq[3] : gq[2], ww = p1 ? gq[2] : gq[3];
            zz += dpp_xor1(ww);
            float uu = p2 ? zz : xx, vv = p2 ? xx : zz;
            uu += dpp_xor2(vv);
            sacc[mq] = uu;
        }
        #pragma unroll
        for (int m = 0; m < 14; ++m) {
            float v = sacc[m];
            v += __shfl_xor(v, 4);
            v += __shfl_xor(v, 8);
            v += __shfl_xor(v, 16);
            v += __shfl_xor(v, 32);
            if (lane < 4) s_gp[wv][m*4 + lane] = v;
        }
    }
    __syncthreads();
    if (t < EEPB)
        s_gate[t] = sigmoid_f(s_gp[0][t] + s_gp[1][t] + s_gp[2][t] + s_gp[3][t] + gate_b2[0]);
    // (s_gate consumed after later barriers)

    // ---- layer 2: a2 = gelu(a1 @ w2 + b2)  [MFMA 32x32x16 bf16] ----
    const int cl = lane & 31;
    const int g  = lane >> 5;
    f32x16 acc00 = zero16(), acc01 = zero16(), acc10 = zero16(), acc11 = zero16();
    {
        const __hip_bfloat16* w2a = w2t + (size_t)((wv*2+0)*32 + cl)*256 + g*8;
        const __hip_bfloat16* w2b = w2t + (size_t)((wv*2+1)*32 + cl)*256 + g*8;
        const __hip_bfloat16* a1a = act + (size_t)(cl)*ARS + g*8;
        const __hip_bfloat16* a1b = act + (size_t)(32+cl)*ARS + g*8;
        #pragma unroll
        for (int kt = 0; kt < 16; ++kt) {
            bf16x8 bfa = *(const bf16x8*)(w2a + kt*16);
            bf16x8 bfb = *(const bf16x8*)(w2b + kt*16);
            bf16x8 afa = *(const bf16x8*)(a1a + kt*16);
            bf16x8 afb = *(const bf16x8*)(a1b + kt*16);
            acc00 = MFMA32(afa, bfa, acc00);
            acc01 = MFMA32(afa, bfb, acc01);
            acc10 = MFMA32(afb, bfa, acc10);
            acc11 = MFMA32(afb, bfb, acc11);
        }
    }
    __syncthreads();   // all a1 reads done -> safe to overwrite act with a2
    {
        const int c0 = (wv*2+0)*32 + cl;
        const int c1 = (wv*2+1)*32 + cl;
        float b20 = msg_b2[c0], b21 = msg_b2[c1];
        #pragma unroll
        for (int r = 0; r < 16; r += 2) {
            int row0 = (r&3) + 8*(r>>2) + 4*g;     // even; pair rows row0, row0+1
            f32x2 v0 = {acc00[r] + b20, acc00[r+1] + b20};
            f32x2 g0 = gelu2(v0);
            act[row0*ARS + c0]     = __float2bfloat16(g0[0]);
            act[(row0+1)*ARS + c0] = __float2bfloat16(g0[1]);
            f32x2 v1 = {acc01[r] + b21, acc01[r+1] + b21};
            f32x2 g1 = gelu2(v1);
            act[row0*ARS + c1]     = __float2bfloat16(g1[0]);
            act[(row0+1)*ARS + c1] = __float2bfloat16(g1[1]);
            if (r < 12) {   // rows 32+row0 >= 56 are pad: skip
                int row1 = 32 + row0;
                f32x2 v2 = {acc10[r] + b20, acc10[r+1] + b20};
                f32x2 g2v = gelu2(v2);
                act[row1*ARS + c0]     = __float2bfloat16(g2v[0]);
                act[(row1+1)*ARS + c0] = __float2bfloat16(g2v[1]);
                f32x2 v3 = {acc11[r] + b21, acc11[r+1] + b21};
                f32x2 g3 = gelu2(v3);
                act[row1*ARS + c1]     = __float2bfloat16(g3[0]);
                act[(row1+1)*ARS + c1] = __float2bfloat16(g3[1]);
            }
        }
    }
    __syncthreads();   // a2 complete

    // ---- layer 3: msg = (a2 @ w3 + b3) * gate  [MFMA 32x32x16 bf16] ----
    f32x16 m0 = zero16(), m1 = zero16();
    {
        const __hip_bfloat16* w3p = w3t + (size_t)(wv*32 + cl)*256 + g*8;
        const __hip_bfloat16* a2a = act + (size_t)(cl)*ARS + g*8;
        const __hip_bfloat16* a2b = act + (size_t)(32+cl)*ARS + g*8;
        #pragma unroll
        for (int kt = 0; kt < 16; ++kt) {
            bf16x8 bfr = *(const bf16x8*)(w3p + kt*16);
            m0 = MFMA32(*(const bf16x8*)(a2a + kt*16), bfr, m0);
            m1 = MFMA32(*(const bf16x8*)(a2b + kt*16), bfr, m1);
        }
    }
    __syncthreads();   // all a2 reads done -> safe to overwrite act with msgbuf
    float* msgbuf = (float*)act;   // [56][MRS] f32
    {
        const int c = wv*32 + cl;
        float b3v = msg_b3[c];
        #pragma unroll
        for (int r = 0; r < 16; r += 2) {
            int row0 = (r&3) + 8*(r>>2) + 4*g;   // even
            f32x2 mm = {m0[r] + b3v, m0[r+1] + b3v};
            f32x2 gt = {s_gate[row0], s_gate[row0+1]};
            mm *= gt;
            msgbuf[row0*MRS + c]     = mm[0];
            msgbuf[(row0+1)*MRS + c] = mm[1];
            int row1 = 32 + row0;
            if (row1 + 1 < EEPB) {
                f32x2 nn = {m1[r] + b3v, m1[r+1] + b3v};
                f32x2 ht = {s_gate[row1], s_gate[row1+1]};
                nn *= ht;
                msgbuf[row1*MRS + c]     = nn[0];
                msgbuf[(row1+1)*MRS + c] = nn[1];
            }
        }
    }
    __syncthreads();

    // ---- aggregate the 7 edges of each node (packed col-pairs, bf16 out) ----
    {
        const int c2  = (t & 63) * 2;
        const int grp = t >> 6;
        #pragma unroll
        for (int p = 0; p < 2; ++p) {
            int nd = grp + p*4;
            f32x2 s = {0.f, 0.f};
            #pragma unroll
            for (int q2 = 0; q2 < 7; ++q2)
                s += *(const f32x2*)&msgbuf[(nd*7+q2)*MRS + c2];
            ushort2 u;
            u.x = (unsigned short)f2bs(s[0]);
            u.y = (unsigned short)f2bs(s[1]);
            *(ushort2*)&AGG[(size_t)(base+nd)*128 + c2] = u;
        }
    }
}

// ---------------- update kernel (MFMA, M=32): u1 (incl h-part), u2, u3 + local + final gelu ----------------
#define UM 32

__global__ __launch_bounds__(256, 4)
void update_kernel(const __hip_bfloat16* __restrict__ w1ut, const __hip_bfloat16* __restrict__ w2ut,
                   const __hip_bfloat16* __restrict__ w3ut, const __hip_bfloat16* __restrict__ wwt,
                   const float* __restrict__ upd_b2, const float* __restrict__ upd_b3,
                   const float* __restrict__ W_b,
                   const float* __restrict__ h, const __hip_bfloat16* __restrict__ AGG,
                   const float* __restrict__ TU,
                   float* __restrict__ out)
{
    __shared__ __align__(16) __hip_bfloat16 ub[UM*ARS];   // [h|agg] -> u1 -> u2, in place
    const int t = threadIdx.x;
    const int lane = t & 63, wv = t >> 6;
    const int cl = lane & 31, g = lane >> 5;
    const int base = blockIdx.x * UM;
    const int b = base >> 12;

    #pragma unroll
    for (int i = 0; i < 4; ++i) {          // stage h tile (32 x 128 f32 -> bf16)
        int f = (i*256 + t)*4;
        int row = f >> 7, col = f & 127;
        float4 hv = *(const float4*)&h[(size_t)base*128 + f];
        s16x4 pk; pk[0]=f2bs(hv.x); pk[1]=f2bs(hv.y); pk[2]=f2bs(hv.z); pk[3]=f2bs(hv.w);
        *(s16x4*)&ub[row*ARS + col] = pk;
    }
    #pragma unroll
    for (int i = 0; i < 2; ++i) {          // stage AGG tile (32 x 128 bf16, direct copy)
        int idx = i*256 + t;               // 32 rows x 16 chunks of 8 bf16
        int row = idx >> 4, ch = idx & 15;
        *(float4*)&ub[row*ARS + 128 + ch*8] =
            *(const float4*)&AGG[(size_t)(base+row)*128 + ch*8];
    }
    __syncthreads();

    // ---- u1 = gelu([h|agg] @ upd_w1[0:256] + TU)  K=256, N=256 ----
    // ---- also HL = h @ W_w (K=128, N=128), kept in registers ----
    f32x16 u0a = zero16(), u1a = zero16(), hl = zero16();
    {
        const __hip_bfloat16* a0 = ub + (size_t)(cl)*ARS + g*8;
        const __hip_bfloat16* b0 = w1ut + (size_t)(wv*64 + cl)*256 + g*8;
        const __hip_bfloat16* b1 = w1ut + (size_t)(wv*64 + 32 + cl)*256 + g*8;
        const __hip_bfloat16* bw = wwt + (size_t)(wv*32 + cl)*128 + g*8;
        #pragma unroll
        for (int kt = 0; kt < 16; ++kt) {
            bf16x8 af = *(const bf16x8*)(a0 + kt*16);
            u0a = MFMA32(af, *(const bf16x8*)(b0 + kt*16), u0a);
            u1a = MFMA32(af, *(const bf16x8*)(b1 + kt*16), u1a);
            if (kt < 8)
                hl = MFMA32(af, *(const bf16x8*)(bw + kt*16), hl);
        }
    }
    __syncthreads();   // staging reads done
    {
        const int c0 = wv*64 + cl, c1 = c0 + 32;
        float tu0 = TU[b*256 + c0], tu1 = TU[b*256 + c1];
        #pragma unroll
        for (int r = 0; r < 16; r += 2) {
            int row = (r&3) + 8*(r>>2) + 4*g;
            f32x2 v0 = {u0a[r] + tu0, u0a[r+1] + tu0};
            f32x2 g0 = gelu2(v0);
            ub[row*ARS + c0]     = __float2bfloat16(g0[0]);
            ub[(row+1)*ARS + c0] = __float2bfloat16(g0[1]);
            f32x2 v1 = {u1a[r] + tu1, u1a[r+1] + tu1};
            f32x2 g1 = gelu2(v1);
            ub[row*ARS + c1]     = __float2bfloat16(g1[0]);
            ub[(row+1)*ARS + c1] = __float2bfloat16(g1[1]);
        }
    }
    __syncthreads();

    // ---- u2 = gelu(u1 @ w2u + b2)  K=256, N=256 ----
    f32x16 v0a = zero16(), v1a = zero16();
    {
        const __hip_bfloat16* a0 = ub + (size_t)(cl)*ARS + g*8;
        const __hip_bfloat16* b0 = w2ut + (size_t)(wv*64 + cl)*256 + g*8;
        const __hip_bfloat16* b1 = w2ut + (size_t)(wv*64 + 32 + cl)*256 + g*8;
        #pragma unroll
        for (int kt = 0; kt < 16; ++kt) {
            bf16x8 af = *(const bf16x8*)(a0 + kt*16);
            v0a = MFMA32(af, *(const bf16x8*)(b0 + kt*16), v0a);
            v1a = MFMA32(af, *(const bf16x8*)(b1 + kt*16), v1a);
        }
    }
    __syncthreads();   // u1 reads done
    {
        const int c0 = wv*64 + cl, c1 = c0 + 32;
        float b20 = upd_b2[c0], b21 = upd_b2[c1];
        #pragma unroll
        for (int r = 0; r < 16; r += 2) {
            int row = (r&3) + 8*(r>>2) + 4*g;
            f32x2 v0 = {v0a[r] + b20, v0a[r+1] + b20};
            f32x2 g0 = gelu2(v0);
            ub[row*ARS + c0]     = __float2bfloat16(g0[0]);
            ub[(row+1)*ARS + c0] = __float2bfloat16(g0[1]);
            f32x2 v1 = {v1a[r] + b21, v1a[r+1] + b21};
            f32x2 g1 = gelu2(v1);
            ub[row*ARS + c1]     = __float2bfloat16(g1[0]);
            ub[(row+1)*ARS + c1] = __float2bfloat16(g1[1]);
        }
    }
    __syncthreads();

    // ---- out = gelu(u2 @ w3u + b3 + HL + W_b)  K=256, N=128 ----
    f32x16 w0a = zero16();
    {
        const __hip_bfloat16* wp = w3ut + (size_t)(wv*32 + cl)*256 + g*8;
        const __hip_bfloat16* a0 = ub + (size_t)(cl)*ARS + g*8;
        #pragma unroll
        for (int kt = 0; kt < 16; ++kt)
            w0a = MFMA32(*(const bf16x8*)(a0 + kt*16), *(const bf16x8*)(wp + kt*16), w0a);
    }
    {
        const int c = wv*32 + cl;
        float b3v = upd_b3[c] + W_b[c];
        #pragma unroll
        for (int r = 0; r < 16; ++r) {
            int row = (r&3) + 8*(r>>2) + 4*g;
            size_t o = (size_t)(base+row)*128 + c;
            out[o] = gelu_f(w0a[r] + b3v + hl[r]);
        }
    }
}

// ---------------- launch ----------------
extern "C" void kernel_launch(void* const* d_in, const int* in_sizes, int n_in,
                              void* d_out, int out_size, void* d_ws, size_t ws_size,
                              hipStream_t stream)
{
    const float* h      = (const float*)d_in[0];
    const float* x      = (const float*)d_in[1];
    const float* tau    = (const float*)d_in[2];
    const float* u0     = (const float*)d_in[3];
    const float* msg_w1 = (const float*)d_in[4];
    const float* msg_b1 = (const float*)d_in[5];
    const float* msg_w2 = (const float*)d_in[6];
    const float* msg_b2 = (const float*)d_in[7];
    const float* msg_w3 = (const float*)d_in[8];
    const float* msg_b3 = (const float*)d_in[9];
    const float* gate_w1= (const float*)d_in[10];
    const float* gate_b1= (const float*)d_in[11];
    const float* gate_w2= (const float*)d_in[12];
    const float* gate_b2= (const float*)d_in[13];
    const float* upd_w1 = (const float*)d_in[14];
    const float* upd_b1 = (const float*)d_in[15];
    const float* upd_w2 = (const float*)d_in[16];
    const float* upd_b2 = (const float*)d_in[17];
    const float* upd_w3 = (const float*)d_in[18];
    const float* upd_b3 = (const float*)d_in[19];
    const float* W_w    = (const float*)d_in[20];
    const float* W_b    = (const float*)d_in[21];
    float* out = (float*)d_out;

    char* ws = (char*)d_ws;
    size_t off = 0;
    auto alloc = [&](size_t bytes) -> void* {
        void* p = ws + off;
        off += (bytes + 255) & ~(size_t)255;
        return p;
    };
    __hip_bfloat16* PAm = (__hip_bfloat16*)alloc((size_t)NNODES*256*2);
    __hip_bfloat16* PBm = (__hip_bfloat16*)alloc((size_t)NNODES*256*2);
    __hip_bfloat16* PAg = (__hip_bfloat16*)alloc((size_t)NNODES*256*2);
    __hip_bfloat16* PBg = (__hip_bfloat16*)alloc((size_t)NNODES*256*2);
    __hip_bfloat16* AGG = (__hip_bfloat16*)alloc((size_t)NNODES*128*2);
    float* TM  = (float*)alloc(8*256*4);
    float* TG  = (float*)alloc(8*256*4);
    float* TU  = (float*)alloc(8*256*4);
    __hip_bfloat16* w2t   = (__hip_bfloat16*)alloc((size_t)256*256*2);
    __hip_bfloat16* w3t   = (__hip_bfloat16*)alloc((size_t)128*256*2);
    __hip_bfloat16* wall_t= (__hip_bfloat16*)alloc((size_t)1024*128*2);
    __hip_bfloat16* w1ut  = (__hip_bfloat16*)alloc((size_t)256*256*2);
    __hip_bfloat16* w2ut  = (__hip_bfloat16*)alloc((size_t)256*256*2);
    __hip_bfloat16* w3ut  = (__hip_bfloat16*)alloc((size_t)128*256*2);
    __hip_bfloat16* wwt   = (__hip_bfloat16*)alloc((size_t)128*128*2);
    (void)ws_size; (void)in_sizes; (void)n_in; (void)out_size;

    wconv_kernel<<<1608, 256, 0, stream>>>(msg_w2, msg_w3, msg_w1, gate_w1,
                                           upd_w1, upd_w2, upd_w3, W_w,
                                           tau, msg_b1, gate_b1, upd_b1,
                                           w2t, w3t, wall_t, w1ut, w2ut, w3ut, wwt,
                                           TM, TG, TU);
    precompute_kernel<<<NNODES/64, 256, 0, stream>>>(h, wall_t,
                                                     PAm, PBm, PAg, PBg);
    edge_kernel<<<NNODES/ENPB, 256, 0, stream>>>(x, u0, msg_w1, gate_w1,
                                                 w2t, msg_b2, w3t, msg_b3,
                                                 gate_w2, gate_b2,
                                                 PAm, PBm, PAg, PBg, TM, TG, AGG);
    update_kernel<<<NNODES/UM, 256, 0, stream>>>(w1ut, w2ut, w3ut, wwt,
                                                 upd_b2, upd_b3, W_b,
                                                 h, AGG, TU, out);
}